// Round 24
// baseline (517.892 us; speedup 1.0000x reference)
//
#include <hip/hip_runtime.h>

#define NN 245760
#define NB 4096
#define NPER 60
#define NE 2000000
#define KSEL 30
#define NDRUG 1024
#define NDIS 2048
#define DCAP 32           // per-node CSR capacity (mean deg 8.14, P(deg>32)~4e-11)

typedef unsigned short ushort_t;
typedef unsigned int uint_t;
using bf16x8 = __attribute__((ext_vector_type(8))) short;
using f32x4 = __attribute__((ext_vector_type(4))) float;

__device__ inline ushort_t f2bf(float f) {
    union { float f; unsigned int u; } v; v.f = f;
    unsigned int r = v.u + 0x7FFF + ((v.u >> 16) & 1);
    return (ushort_t)(r >> 16);
}

// ---------------- CSR build: single-pass direct scatter (fixed-capacity rows) ----------------
__global__ __launch_bounds__(256) void k_edge_scatter(const int* __restrict__ ei,
                                                      int* __restrict__ cnt,
                                                      int* __restrict__ csr) {
    int idx = blockIdx.x * 256 + threadIdx.x;
    int stride = gridDim.x * 256;
    for (int e = idx; e < NE; e += stride) {
        int s = ei[e], d = ei[NE + e];
        int pos = atomicAdd(&cnt[d], 1);
        if (pos < DCAP) csr[(long)d * DCAP + pos] = s;
    }
}

__global__ void k_dinv(const int* __restrict__ cnt, float* __restrict__ dinv) {
    int n = blockIdx.x * 256 + threadIdx.x;
    if (n < NN) dinv[n] = 1.0f / sqrtf((float)cnt[n] + 1.0f);
}

// ---------------- X(M x K, stride lda) @ W(K x 32) -> h(M x 32), K<=64 ----------------
__global__ __launch_bounds__(256) void k_xw(const float* __restrict__ A, const float* __restrict__ W,
                                            float* __restrict__ h, int K, int lda) {
    __shared__ float Xs[64][65];
    __shared__ float Ws[64][32];
    int t = threadIdx.x;
    int r0 = blockIdx.x * 64;
    int kq = K >> 2;
    for (int idx = t; idx < 64 * kq; idx += 256) {
        int row = idx / kq, q = idx % kq;
        float4 v = *(const float4*)(A + (long)(r0 + row) * lda + q * 4);
        Xs[row][q * 4 + 0] = v.x; Xs[row][q * 4 + 1] = v.y;
        Xs[row][q * 4 + 2] = v.z; Xs[row][q * 4 + 3] = v.w;
    }
    for (int idx = t; idx < K * 32; idx += 256) ((float*)Ws)[idx] = W[idx];
    __syncthreads();
    int r = (t >> 3) * 2, c = (t & 7) * 4;
    float4 acc0 = {0, 0, 0, 0}, acc1 = {0, 0, 0, 0};
    for (int k = 0; k < K; k++) {
        float x0 = Xs[r][k], x1 = Xs[r + 1][k];
        float4 w = *(const float4*)&Ws[k][c];
        acc0.x += x0 * w.x; acc0.y += x0 * w.y; acc0.z += x0 * w.z; acc0.w += x0 * w.w;
        acc1.x += x1 * w.x; acc1.y += x1 * w.y; acc1.z += x1 * w.z; acc1.w += x1 * w.w;
    }
    *(float4*)(h + (long)(r0 + r) * 32 + c) = acc0;
    *(float4*)(h + (long)(r0 + r + 1) * 32 + c) = acc1;
}

// ---------------- GCN aggregation: batched-edge gather (8 loads in flight per group) ----------------
__global__ void k_gcn_agg(const float* __restrict__ h, const int* __restrict__ csr,
                          const int* __restrict__ cnt,
                          const float* __restrict__ dinv, const float* __restrict__ bias,
                          float* __restrict__ out, int colofs) {
    int t = threadIdx.x;
    int l = t & 7, g = t >> 3;
    int wl = t & 63;                 // lane within wave
    int gbase = wl & ~7;             // first lane of this 8-lane group
    int d = blockIdx.x * 32 + g;
    float dd = dinv[d];
    int start = d * DCAP;
    int c = cnt[d]; if (c > DCAP) c = DCAP;
    float4 hv = *(const float4*)(h + (long)d * 32 + l * 4);
    float4 acc; acc.x = dd * hv.x; acc.y = dd * hv.y; acc.z = dd * hv.z; acc.w = dd * hv.w;
    int k = 0;
    while (k < c) {
        int nb = c - k; if (nb > 8) nb = 8;
        int sl = (l < nb) ? csr[start + k + l] : 0;
        int sj[8]; float ds[8]; float4 hj[8];
#pragma unroll
        for (int j = 0; j < 8; j++)
            sj[j] = __shfl(sl, gbase + j, 64);
#pragma unroll
        for (int j = 0; j < 8; j++)
            if (j < nb) ds[j] = dinv[sj[j]];
#pragma unroll
        for (int j = 0; j < 8; j++)
            if (j < nb) hj[j] = *(const float4*)(h + (long)sj[j] * 32 + l * 4);
#pragma unroll
        for (int j = 0; j < 8; j++) {
            if (j < nb) {
                acc.x += ds[j] * hj[j].x;
                acc.y += ds[j] * hj[j].y;
                acc.z += ds[j] * hj[j].z;
                acc.w += ds[j] * hj[j].w;
            }
        }
        k += nb;
    }
    float4 bv = *(const float4*)(bias + l * 4);
    float* op = out + (long)d * 64 + colofs + l * 4;
    op[0] = fmaxf(dd * acc.x + bv.x, 0.f);
    op[1] = fmaxf(dd * acc.y + bv.y, 0.f);
    op[2] = fmaxf(dd * acc.z + bv.z, 0.f);
    op[3] = fmaxf(dd * acc.w + bv.w, 0.f);
}

// ---------------- conv1 via bf16 MFMA: gather + relu + pool, LDS-staged coalesced flush ----------------
__global__ __launch_bounds__(256, 2) void k_conv1_mfma(const float* __restrict__ cs,
                                                       const int* __restrict__ sel,
                                                       const ushort_t* __restrict__ c1w16,
                                                       const float* __restrict__ c1b,
                                                       ushort_t* __restrict__ po16) {
    __shared__ ushort_t A_lds[128 * 72];
    __shared__ ushort_t B_lds[128 * 72];
    int t = threadIdx.x;
    int r0 = blockIdx.x * 128;
#pragma unroll
    for (int rnd = 0; rnd < 4; rnd++) {
        int idx = t + rnd * 256;
        int row = idx >> 3, seg = idx & 7;
        const float* src = cs + (long)sel[r0 + row] * 64 + seg * 8;
        float4 v0 = *(const float4*)src;
        float4 v1 = *(const float4*)(src + 4);
        ushort_t tmp[8] = {f2bf(v0.x), f2bf(v0.y), f2bf(v0.z), f2bf(v0.w),
                           f2bf(v1.x), f2bf(v1.y), f2bf(v1.z), f2bf(v1.w)};
        *(uint4*)&A_lds[row * 72 + seg * 8] = *(uint4*)tmp;
        *(uint4*)&B_lds[row * 72 + seg * 8] = *(const uint4*)(c1w16 + row * 64 + seg * 8);
    }
    __syncthreads();
    int wv = t >> 6, lane = t & 63;
    int wm = wv >> 1, wn = wv & 1;
    int lrow = lane & 15, lk = (lane >> 4) * 8, lr4 = (lane >> 4) * 4;
    f32x4 acc[4][4] = {};
#pragma unroll
    for (int kk = 0; kk < 2; kk++) {
        bf16x8 a[4], b[4];
#pragma unroll
        for (int f = 0; f < 4; f++) {
            a[f] = *(const bf16x8*)&A_lds[(wm * 64 + f * 16 + lrow) * 72 + kk * 32 + lk];
            b[f] = *(const bf16x8*)&B_lds[(wn * 64 + f * 16 + lrow) * 72 + kk * 32 + lk];
        }
#pragma unroll
        for (int i = 0; i < 4; i++)
#pragma unroll
            for (int j = 0; j < 4; j++)
                acc[i][j] = __builtin_amdgcn_mfma_f32_16x16x32_bf16(a[i], b[j], acc[i][j], 0, 0, 0);
    }
    __syncthreads();                       // MFMA operands consumed; reuse A_lds for pooled tile
    ushort_t* po_lds = A_lds;              // 64 x 128 ushorts = 8192 <= 9216
#pragma unroll
    for (int fn = 0; fn < 4; fn++) {
        int col = wn * 64 + fn * 16 + lrow;
        float bb = c1b[col];
#pragma unroll
        for (int fm = 0; fm < 4; fm++) {
            int lrow2 = wm * 32 + fm * 8 + (lr4 >> 1);   // even
            float v0 = fmaxf(acc[fm][fn][0] + bb, 0.f);
            float v1 = fmaxf(acc[fm][fn][1] + bb, 0.f);
            float v2 = fmaxf(acc[fm][fn][2] + bb, 0.f);
            float v3 = fmaxf(acc[fm][fn][3] + bb, 0.f);
            po_lds[lrow2 * 128 + col]       = f2bf(fmaxf(v0, v1));
            po_lds[(lrow2 + 1) * 128 + col] = f2bf(fmaxf(v2, v3));
        }
    }
    __syncthreads();
    uint4* dst = (uint4*)(po16 + (long)(r0 >> 1) * 128);
    const uint4* srcp = (const uint4*)po_lds;
#pragma unroll
    for (int i = 0; i < 4; i++) dst[t + i * 256] = srcp[t + i * 256];
}

// ---------------- conv2: bf16 MFMA im2col GEMM (direct LDS staging, LDS-staged C flush) ----------------
__global__ __launch_bounds__(256, 2) void k_conv2_mfma(const ushort_t* __restrict__ pool16,
                                                       const ushort_t* __restrict__ w2colT,
                                                       ushort_t* __restrict__ act2,
                                                       const float* __restrict__ bias) {
    __shared__ ushort_t smem[2 * 128 * 72];   // A | B ; reused as 128x128 C-tile
    ushort_t* A_lds = smem;
    ushort_t* B_lds = smem + 128 * 72;
    int t = threadIdx.x;
    int r0 = blockIdx.x * 128, c0 = blockIdx.y * 128;
    long abase[4]; const ushort_t* bptr[4]; int lofs[4];
#pragma unroll
    for (int rnd = 0; rnd < 4; rnd++) {
        int idx = t + rnd * 256;
        int row = idx >> 3, seg = idx & 7;
        int arow = r0 + row;
        int bb = arow / 11, tt2 = arow - bb * 11;
        abase[rnd] = (long)(bb * 15 + tt2) * 128 + seg * 8;
        bptr[rnd] = w2colT + (long)(c0 + row) * 640 + seg * 8;
        lofs[rnd] = row * 72 + seg * 8;
    }
    int wv = t >> 6, lane = t & 63;
    int wm = wv >> 1, wn = wv & 1;
    int lrow = lane & 15, lk = (lane >> 4) * 8, lr4 = (lane >> 4) * 4;
    f32x4 acc[4][4] = {};
    for (int k0 = 0; k0 < 640; k0 += 64) {
#pragma unroll
        for (int rnd = 0; rnd < 4; rnd++) {
            *(uint4*)&A_lds[lofs[rnd]] = *(const uint4*)(pool16 + abase[rnd] + k0);
            *(uint4*)&B_lds[lofs[rnd]] = *(const uint4*)(bptr[rnd] + k0);
        }
        __syncthreads();
#pragma unroll
        for (int kk = 0; kk < 2; kk++) {
            bf16x8 a[4], b[4];
#pragma unroll
            for (int f = 0; f < 4; f++) {
                a[f] = *(const bf16x8*)&A_lds[(wm * 64 + f * 16 + lrow) * 72 + kk * 32 + lk];
                b[f] = *(const bf16x8*)&B_lds[(wn * 64 + f * 16 + lrow) * 72 + kk * 32 + lk];
            }
#pragma unroll
            for (int i = 0; i < 4; i++)
#pragma unroll
                for (int j = 0; j < 4; j++)
                    acc[i][j] = __builtin_amdgcn_mfma_f32_16x16x32_bf16(a[i], b[j], acc[i][j], 0, 0, 0);
        }
        __syncthreads();
    }
    // stage C-tile (128x128 bf16) in LDS, flush coalesced
    ushort_t* c_lds = smem;
#pragma unroll
    for (int fn = 0; fn < 4; fn++) {
        int col = wn * 64 + fn * 16 + lrow;
        float bv = bias[c0 + col];
#pragma unroll
        for (int fm = 0; fm < 4; fm++) {
            int lr = wm * 64 + fm * 16 + lr4;
#pragma unroll
            for (int j = 0; j < 4; j++)
                c_lds[(lr + j) * 128 + col] = f2bf(fmaxf(acc[fm][fn][j] + bv, 0.f));
        }
    }
    __syncthreads();
#pragma unroll
    for (int i = 0; i < 8; i++) {
        int idx = t + i * 256;          // 0..2047
        int row = idx >> 4, q = idx & 15;
        *(uint4*)(act2 + (long)(r0 + row) * 256 + c0 + q * 8) = ((const uint4*)c_lds)[idx];
    }
}

// ---------------- lin1: bf16 MFMA split-K, fp32 atomic epilogue (direct LDS staging) ----------------
__global__ __launch_bounds__(256, 2) void k_lin1_mfma(const ushort_t* __restrict__ A,
                                                      const ushort_t* __restrict__ Bm,
                                                      float* __restrict__ C) {
    __shared__ ushort_t A_lds[128 * 72];
    __shared__ ushort_t B_lds[128 * 72];
    int t = threadIdx.x;
    int r0 = blockIdx.x * 128;
    int kz = blockIdx.z;
    const ushort_t* ap[4]; const ushort_t* bp[4]; int lofs[4];
#pragma unroll
    for (int rnd = 0; rnd < 4; rnd++) {
        int idx = t + rnd * 256;
        int row = idx >> 3, seg = idx & 7;
        ap[rnd] = A + (long)(r0 + row) * 2816 + kz * 704 + seg * 8;
        bp[rnd] = Bm + (long)row * 2816 + kz * 704 + seg * 8;
        lofs[rnd] = row * 72 + seg * 8;
    }
    int wv = t >> 6, lane = t & 63;
    int wm = wv >> 1, wn = wv & 1;
    int lrow = lane & 15, lk = (lane >> 4) * 8, lr4 = (lane >> 4) * 4;
    f32x4 acc[4][4] = {};
    for (int k0 = 0; k0 < 704; k0 += 64) {
#pragma unroll
        for (int rnd = 0; rnd < 4; rnd++) {
            *(uint4*)&A_lds[lofs[rnd]] = *(const uint4*)(ap[rnd] + k0);
            *(uint4*)&B_lds[lofs[rnd]] = *(const uint4*)(bp[rnd] + k0);
        }
        __syncthreads();
#pragma unroll
        for (int kk = 0; kk < 2; kk++) {
            bf16x8 a[4], b[4];
#pragma unroll
            for (int f = 0; f < 4; f++) {
                a[f] = *(const bf16x8*)&A_lds[(wm * 64 + f * 16 + lrow) * 72 + kk * 32 + lk];
                b[f] = *(const bf16x8*)&B_lds[(wn * 64 + f * 16 + lrow) * 72 + kk * 32 + lk];
            }
#pragma unroll
            for (int i = 0; i < 4; i++)
#pragma unroll
                for (int j = 0; j < 4; j++)
                    acc[i][j] = __builtin_amdgcn_mfma_f32_16x16x32_bf16(a[i], b[j], acc[i][j], 0, 0, 0);
        }
        __syncthreads();
    }
#pragma unroll
    for (int fn = 0; fn < 4; fn++) {
        int col = wn * 64 + fn * 16 + lrow;
#pragma unroll
        for (int fm = 0; fm < 4; fm++) {
            int rowb = r0 + wm * 64 + fm * 16 + lr4;
#pragma unroll
            for (int j = 0; j < 4; j++)
                atomicAdd(&C[(long)(rowb + j) * 128 + col], acc[fm][fn][j]);
        }
    }
}

// ---------------- de = sim @ lin_w + b : bf16 MFMA, split-K, atomic fp32 epilogue ----------------
__global__ __launch_bounds__(256, 2) void k_de_mfma(
    const ushort_t* __restrict__ A0, const ushort_t* __restrict__ B0, float* __restrict__ C0,
    const float* __restrict__ bias0, int M0, int K0, int KS0,
    const ushort_t* __restrict__ A1, const ushort_t* __restrict__ B1, float* __restrict__ C1,
    const float* __restrict__ bias1, int M1, int K1, int KS1) {
    __shared__ ushort_t A_lds[128 * 72];
    __shared__ ushort_t B_lds[64 * 72];
    int z = blockIdx.z;
    const ushort_t* A; const ushort_t* Bm; float* C; const float* bias; int M, K, kz, KS;
    if (z < KS0) { A = A0; Bm = B0; C = C0; bias = bias0; M = M0; K = K0; kz = z; KS = KS0; }
    else { A = A1; Bm = B1; C = C1; bias = bias1; M = M1; K = K1; kz = z - KS0; KS = KS1; }
    int r0 = blockIdx.x * 128, c0 = blockIdx.y * 64;
    if (r0 >= M) return;
    int Kc = K / KS;
    int kb = kz * Kc;
    int t = threadIdx.x;
    const ushort_t* ap[4]; int alofs[4];
#pragma unroll
    for (int rnd = 0; rnd < 4; rnd++) {
        int idx = t + rnd * 256;
        int row = idx >> 3, seg = idx & 7;
        ap[rnd] = A + (long)(r0 + row) * K + kb + seg * 8;
        alofs[rnd] = row * 72 + seg * 8;
    }
    const ushort_t* bp[2]; int blofs[2];
#pragma unroll
    for (int rnd = 0; rnd < 2; rnd++) {
        int idx = t + rnd * 256;
        int row = idx >> 3, seg = idx & 7;
        bp[rnd] = Bm + (long)(c0 + row) * K + kb + seg * 8;
        blofs[rnd] = row * 72 + seg * 8;
    }
    int wv = t >> 6, lane = t & 63;
    int lrow = lane & 15, lk = (lane >> 4) * 8, lr4 = (lane >> 4) * 4;
    uint4 areg[4], breg[2];
#pragma unroll
    for (int rnd = 0; rnd < 4; rnd++) areg[rnd] = *(const uint4*)(ap[rnd]);
#pragma unroll
    for (int rnd = 0; rnd < 2; rnd++) breg[rnd] = *(const uint4*)(bp[rnd]);
    f32x4 acc[2][4] = {};
    for (int k0 = 0; k0 < Kc; k0 += 64) {
#pragma unroll
        for (int rnd = 0; rnd < 4; rnd++) *(uint4*)&A_lds[alofs[rnd]] = areg[rnd];
#pragma unroll
        for (int rnd = 0; rnd < 2; rnd++) *(uint4*)&B_lds[blofs[rnd]] = breg[rnd];
        __syncthreads();
        if (k0 + 64 < Kc) {
#pragma unroll
            for (int rnd = 0; rnd < 4; rnd++) areg[rnd] = *(const uint4*)(ap[rnd] + k0 + 64);
#pragma unroll
            for (int rnd = 0; rnd < 2; rnd++) breg[rnd] = *(const uint4*)(bp[rnd] + k0 + 64);
        }
#pragma unroll
        for (int kk = 0; kk < 2; kk++) {
            bf16x8 a[2], b[4];
#pragma unroll
            for (int f = 0; f < 2; f++)
                a[f] = *(const bf16x8*)&A_lds[(wv * 32 + f * 16 + lrow) * 72 + kk * 32 + lk];
#pragma unroll
            for (int f = 0; f < 4; f++)
                b[f] = *(const bf16x8*)&B_lds[(f * 16 + lrow) * 72 + kk * 32 + lk];
#pragma unroll
            for (int i = 0; i < 2; i++)
#pragma unroll
                for (int j = 0; j < 4; j++)
                    acc[i][j] = __builtin_amdgcn_mfma_f32_16x16x32_bf16(a[i], b[j], acc[i][j], 0, 0, 0);
        }
        __syncthreads();
    }
#pragma unroll
    for (int fn = 0; fn < 4; fn++) {
        int col = c0 + fn * 16 + lrow;
        float bv = (kz == 0) ? bias[col] : 0.f;
#pragma unroll
        for (int fm = 0; fm < 2; fm++) {
            int rowb = r0 + wv * 32 + fm * 16 + lr4;
#pragma unroll
            for (int j = 0; j < 4; j++)
                atomicAdd(&C[(long)(rowb + j) * 256 + col], acc[fm][fn][j] + bv);
        }
    }
}

// ---------------- g = adj @ u : bf16 MFMA, N=64, split-K, atomic fp32 epilogue ----------------
__global__ __launch_bounds__(256, 2) void k_g_mfma(
    const ushort_t* __restrict__ A0, const ushort_t* __restrict__ B0, float* __restrict__ C0,
    int M0, int K0, int KS0,
    const ushort_t* __restrict__ A1, const ushort_t* __restrict__ B1, float* __restrict__ C1,
    int M1, int K1, int KS1) {
    __shared__ ushort_t A_lds[128 * 72];
    __shared__ ushort_t B_lds[64 * 72];
    int z = blockIdx.z;
    const ushort_t* A; const ushort_t* Bm; float* C; int M, K, kz, KS;
    if (z < KS0) { A = A0; Bm = B0; C = C0; M = M0; K = K0; kz = z; KS = KS0; }
    else { A = A1; Bm = B1; C = C1; M = M1; K = K1; kz = z - KS0; KS = KS1; }
    int r0 = blockIdx.x * 128;
    if (r0 >= M) return;
    int Kc = K / KS;
    int kb = kz * Kc;
    int t = threadIdx.x;
    const ushort_t* ap[4]; int alofs[4];
#pragma unroll
    for (int rnd = 0; rnd < 4; rnd++) {
        int idx = t + rnd * 256;
        int row = idx >> 3, seg = idx & 7;
        ap[rnd] = A + (long)(r0 + row) * K + kb + seg * 8;
        alofs[rnd] = row * 72 + seg * 8;
    }
    const ushort_t* bp[2]; int blofs[2];
#pragma unroll
    for (int rnd = 0; rnd < 2; rnd++) {
        int idx = t + rnd * 256;
        int row = idx >> 3, seg = idx & 7;
        bp[rnd] = Bm + (long)row * K + kb + seg * 8;
        blofs[rnd] = row * 72 + seg * 8;
    }
    int wv = t >> 6, lane = t & 63;
    int lrow = lane & 15, lk = (lane >> 4) * 8, lr4 = (lane >> 4) * 4;
    uint4 areg[4], breg[2];
#pragma unroll
    for (int rnd = 0; rnd < 4; rnd++) areg[rnd] = *(const uint4*)(ap[rnd]);
#pragma unroll
    for (int rnd = 0; rnd < 2; rnd++) breg[rnd] = *(const uint4*)(bp[rnd]);
    f32x4 acc[2][4] = {};
    for (int k0 = 0; k0 < Kc; k0 += 64) {
#pragma unroll
        for (int rnd = 0; rnd < 4; rnd++) *(uint4*)&A_lds[alofs[rnd]] = areg[rnd];
#pragma unroll
        for (int rnd = 0; rnd < 2; rnd++) *(uint4*)&B_lds[blofs[rnd]] = breg[rnd];
        __syncthreads();
        if (k0 + 64 < Kc) {
#pragma unroll
            for (int rnd = 0; rnd < 4; rnd++) areg[rnd] = *(const uint4*)(ap[rnd] + k0 + 64);
#pragma unroll
            for (int rnd = 0; rnd < 2; rnd++) breg[rnd] = *(const uint4*)(bp[rnd] + k0 + 64);
        }
#pragma unroll
        for (int kk = 0; kk < 2; kk++) {
            bf16x8 a[2], b[4];
#pragma unroll
            for (int f = 0; f < 2; f++)
                a[f] = *(const bf16x8*)&A_lds[(wv * 32 + f * 16 + lrow) * 72 + kk * 32 + lk];
#pragma unroll
            for (int f = 0; f < 4; f++)
                b[f] = *(const bf16x8*)&B_lds[(f * 16 + lrow) * 72 + kk * 32 + lk];
#pragma unroll
            for (int i = 0; i < 2; i++)
#pragma unroll
                for (int j = 0; j < 4; j++)
                    acc[i][j] = __builtin_amdgcn_mfma_f32_16x16x32_bf16(a[i], b[j], acc[i][j], 0, 0, 0);
        }
        __syncthreads();
    }
#pragma unroll
    for (int fn = 0; fn < 4; fn++) {
        int col = fn * 16 + lrow;
#pragma unroll
        for (int fm = 0; fm < 2; fm++) {
            int rowb = r0 + wv * 32 + fm * 16 + lr4;
#pragma unroll
            for (int j = 0; j < 4; j++)
                atomicAdd(&C[(long)(rowb + j) * 64 + col], acc[fm][fn][j]);
        }
    }
}

// ---------------- conversions ----------------
__global__ void k_cvt2(const float* __restrict__ a0, ushort_t* __restrict__ o0, long n0,
                       const float* __restrict__ a1, ushort_t* __restrict__ o1, long n1) {
    long i4 = ((long)blockIdx.x * 256 + threadIdx.x) * 4;
    const float* a; ushort_t* o;
    if (i4 < n0) { a = a0 + i4; o = o0 + i4; }
    else {
        long j = i4 - n0;
        if (j >= n1) return;
        a = a1 + j; o = o1 + j;
    }
    float4 v = *(const float4*)a;
    o[0] = f2bf(v.x); o[1] = f2bf(v.y); o[2] = f2bf(v.z); o[3] = f2bf(v.w);
}

// lin_w (K x 256) -> bf16 transposed [n][k]; LDS tile transpose, dual problem
__global__ void k_linwT2(const float* __restrict__ w0, ushort_t* __restrict__ o0, int K0,
                         const float* __restrict__ w1, ushort_t* __restrict__ o1, int K1) {
    __shared__ float tile[64][65];
    int nb0 = K0 / 64;
    int bx = blockIdx.x;
    const float* w; ushort_t* o; int K, kt;
    if (bx < nb0) { w = w0; o = o0; K = K0; kt = bx; }
    else { w = w1; o = o1; K = K1; kt = bx - nb0; }
    int n0 = blockIdx.y * 64, k0 = kt * 64;
    int t = threadIdx.x;
    int r = t >> 6, c = t & 63;
    for (int rr = r; rr < 64; rr += 4)
        tile[rr][c] = w[(long)(k0 + rr) * 256 + n0 + c];
    __syncthreads();
    for (int rr = r; rr < 64; rr += 4)
        o[(long)(n0 + rr) * K + k0 + c] = f2bf(tile[c][rr]);
}

// u (K x 64) -> uT bf16 [64][K]; dual problem
__global__ void k_uT2(const float* __restrict__ u0, ushort_t* __restrict__ o0, int K0,
                      const float* __restrict__ u1, ushort_t* __restrict__ o1, int K1) {
    __shared__ float tile[64][65];
    int nb0 = K0 / 64;
    int bx = blockIdx.x;
    const float* u; ushort_t* o; int K, kt;
    if (bx < nb0) { u = u0; o = o0; K = K0; kt = bx; }
    else { u = u1; o = o1; K = K1; kt = bx - nb0; }
    int k0 = kt * 64;
    int t = threadIdx.x;
    int r = t >> 6, c = t & 63;
    for (int rr = r; rr < 64; rr += 4)
        tile[rr][c] = u[(long)(k0 + rr) * 64 + c];
    __syncthreads();
    for (int rr = r; rr < 64; rr += 4)
        o[(long)rr * K + k0 + c] = f2bf(tile[c][rr]);
}

// ---------------- dual-problem split-K 64x64 GEMM (fp32, register-prefetched K-loop) ----------------
__global__ __launch_bounds__(256) void k_gemm_sk(
    const float* A0, const float* B0, float* C0, const float* ab0p, const float* cs0p,
    int M0, int N0, int K0, int lda0, int KS0, int Kc0,
    const float* A1, const float* B1, float* C1, const float* ab1p, const float* cs1p,
    int M1, int N1, int K1, int lda1, int KS1, int Kc1) {
    int z = blockIdx.z;
    const float* A; const float* Bm; float* C; const float* abp; const float* csp;
    int M, N, K, lda, kz, Kc;
    if (z < KS0) { A = A0; Bm = B0; C = C0; abp = ab0p; csp = cs0p; M = M0; N = N0; K = K0; lda = lda0; kz = z; Kc = Kc0; }
    else { A = A1; Bm = B1; C = C1; abp = ab1p; csp = cs1p; M = M1; N = N1; K = K1; lda = lda1; kz = z - KS0; Kc = Kc1; }
    int r0 = blockIdx.x * 64, c0 = blockIdx.y * 64;
    if (r0 >= M || c0 >= N) return;
    int kb = kz * Kc, ke = min(K, kb + Kc);
    __shared__ float As[16][68];
    __shared__ float Bs[16][68];
    int t = threadIdx.x;
    int tx = t & 15, ty = t >> 4;
    float acc[4][4] = {};
    int ar = t >> 2, aq = (t & 3) * 4;
    long abase = (long)(r0 + ar) * lda;
    int brow = t >> 4, bc = (t & 15) * 4;
    // prefetch first K-step
    float4 av = *(const float4*)(A + abase + kb + aq);
    if (abp) {
        float4 abv = *(const float4*)(abp + kb + aq);
        av.x += abv.x; av.y += abv.y; av.z += abv.z; av.w += abv.w;
    }
    float4 bv = *(const float4*)(Bm + (long)(kb + brow) * N + c0 + bc);
    for (int k0 = kb; k0 < ke; k0 += 16) {
        As[aq + 0][ar] = av.x; As[aq + 1][ar] = av.y; As[aq + 2][ar] = av.z; As[aq + 3][ar] = av.w;
        *(float4*)&Bs[brow][bc] = bv;
        __syncthreads();
        if (k0 + 16 < ke) {
            av = *(const float4*)(A + abase + k0 + 16 + aq);
            if (abp) {
                float4 abv = *(const float4*)(abp + k0 + 16 + aq);
                av.x += abv.x; av.y += abv.y; av.z += abv.z; av.w += abv.w;
            }
            bv = *(const float4*)(Bm + (long)(k0 + 16 + brow) * N + c0 + bc);
        }
#pragma unroll
        for (int kk = 0; kk < 16; kk++) {
            float4 a4 = *(const float4*)&As[kk][ty * 4];
            float4 b4 = *(const float4*)&Bs[kk][tx * 4];
            float aa[4] = {a4.x, a4.y, a4.z, a4.w};
            float bb2[4] = {b4.x, b4.y, b4.z, b4.w};
#pragma unroll
            for (int i = 0; i < 4; i++)
#pragma unroll
                for (int j = 0; j < 4; j++) acc[i][j] += aa[i] * bb2[j];
        }
        __syncthreads();
    }
#pragma unroll
    for (int i = 0; i < 4; i++) {
        int row = r0 + ty * 4 + i;
        float sc = csp ? csp[row] : 1.0f;
#pragma unroll
        for (int j = 0; j < 4; j++)
            atomicAdd(&C[(long)row * N + c0 + tx * 4 + j], acc[i][j] * sc);
    }
}

// ---------------- dense-path fused pieces ----------------
__global__ void k_dense_deg2(const float* __restrict__ adj0, float* __restrict__ d0, int n0,
                             const float* __restrict__ adj1, float* __restrict__ d1, int n1) {
    int lane = threadIdx.x & 63;
    int row = (blockIdx.x * blockDim.x + threadIdx.x) >> 6;
    const float* adj; float* dv; int n, r;
    if (row < n0) { adj = adj0; dv = d0; n = n0; r = row; }
    else {
        r = row - n0;
        if (r >= n1) return;
        adj = adj1; dv = d1; n = n1;
    }
    const float* rp = adj + (long)r * n;
    float s = 0.f;
    for (int j = lane; j < n; j += 64) s += rp[j];
    for (int off = 32; off > 0; off >>= 1) s += __shfl_down(s, off, 64);
    if (lane == 0) {
        float deg = s - rp[r] + 1.0f;
        dv[r] = (deg > 0.f) ? 1.0f / sqrtf(deg) : 0.f;
    }
}

__global__ void k_fix_w4(const float* g0, const float* u0, const float* adj0, const float* d0, float* o0, int n0,
                         const float* g1, const float* u1, const float* adj1, const float* d1, float* o1, int n1,
                         const float* __restrict__ b3, const float* __restrict__ W4) {
    __shared__ float dfs[16][68];
    __shared__ float W4s[64 * 16];
    int t = threadIdx.x;
    for (int i = t; i < 1024; i += 256) W4s[i] = W4[i];
    int bx = blockIdx.x, nb0 = n0 / 16;
    const float* g; const float* u; const float* adj; const float* dv; float* o; int n, r0;
    if (bx < nb0) { g = g0; u = u0; adj = adj0; dv = d0; o = o0; n = n0; r0 = bx * 16; }
    else { g = g1; u = u1; adj = adj1; dv = d1; o = o1; n = n1; r0 = (bx - nb0) * 16; }
    int r = t >> 4;
    int row = r0 + r;
    float di = dv[row];
    float om = 1.0f - adj[(long)row * n + row];
    int c4 = (t & 15) * 4;
    float4 gv = *(const float4*)(g + (long)row * 64 + c4);
    float4 uv = *(const float4*)(u + (long)row * 64 + c4);
    float4 bv = *(const float4*)(b3 + c4);
    dfs[r][c4 + 0] = fmaxf(di * (gv.x + om * uv.x) + bv.x, 0.f);
    dfs[r][c4 + 1] = fmaxf(di * (gv.y + om * uv.y) + bv.y, 0.f);
    dfs[r][c4 + 2] = fmaxf(di * (gv.z + om * uv.z) + bv.z, 0.f);
    dfs[r][c4 + 3] = fmaxf(di * (gv.w + om * uv.w) + bv.w, 0.f);
    __syncthreads();
    int c = t & 15;
    float accv = 0.f;
#pragma unroll
    for (int k = 0; k < 64; k++) accv += dfs[r][k] * W4s[k * 16 + c];
    o[row * 16 + c] = di * accv;
}

__global__ void k_fixup2(const float* g0, const float* t0, const float* adj0, const float* d0, float* C0, long n0,
                         const float* g1, const float* t1, const float* adj1, const float* d1, float* C1, long n1,
                         const float* bias, int cols) {
    long idx = (long)blockIdx.x * 256 + threadIdx.x;
    long s0 = n0 * cols;
    const float* g; const float* tt; const float* adj; const float* dv; float* C; long n, li;
    if (idx < s0) { g = g0; tt = t0; adj = adj0; dv = d0; C = C0; n = n0; li = idx; }
    else {
        li = idx - s0;
        if (li >= n1 * cols) return;
        g = g1; tt = t1; adj = adj1; dv = d1; C = C1; n = n1;
    }
    long i = li / cols; int j = li % cols;
    float v = dv[i] * (g[li] + (1.0f - adj[i * n + i]) * tt[li]) + bias[j];
    C[li] = fmaxf(v, 0.f);
}

__global__ void k_adj16(const float* adj0, const float* u0, float* C0, int n0, int KS0, int Kc0,
                        const float* adj1, const float* u1, float* C1, int n1, int KS1, int Kc1) {
    int z = blockIdx.z;
    const float* adj; const float* u; float* C; int n, kz, Kc;
    if (z < KS0) { adj = adj0; u = u0; C = C0; n = n0; kz = z; Kc = Kc0; }
    else { adj = adj1; u = u1; C = C1; n = n1; kz = z - KS0; Kc = Kc1; }
    int r0 = blockIdx.x * 16;
    if (r0 >= n) return;
    int t = threadIdx.x;
    int r = r0 + (t >> 4), c = t & 15;
    int kb = kz * Kc, ke = min(n, kb + Kc);
    const float* arp = adj + (long)r * n;
    float acc = 0.f;
    for (int k = kb; k < ke; k += 4) {
        float4 a = *(const float4*)(arp + k);
        acc += a.x * u[(k + 0) * 16 + c] + a.y * u[(k + 1) * 16 + c]
             + a.z * u[(k + 2) * 16 + c] + a.w * u[(k + 3) * 16 + c];
    }
    atomicAdd(&C[r * 16 + c], acc);
}

// ---------------- stable top-K selection ----------------
__global__ void k_select(const float* __restrict__ cs, int* __restrict__ sel) {
    __shared__ float kk[240];
    int t = threadIdx.x;
    int b0 = blockIdx.x * 4;
    if (t < 240) kk[t] = cs[((long)(b0 * 60 + t)) * 64 + 63];
    __syncthreads();
    if (t < 240) {
        int lb = t / 60, i = t % 60;
        float key = kk[lb * 60 + i];
        int r = 0;
        for (int j = 0; j < 60; j++) {
            float kj = kk[lb * 60 + j];
            r += (kj > key) || (kj == key && j < i);
        }
        if (r < KSEL) sel[(b0 + lb) * KSEL + r] = (b0 + lb) * 60 + i;
    }
}

// ---------------- weight prep (bf16, transposed [out][k]) ----------------
__global__ void k_w2colT(const float* __restrict__ c2w, ushort_t* __restrict__ o) {
    int idx = blockIdx.x * blockDim.x + threadIdx.x;
    if (idx >= 256 * 640) return;
    int oc = idx / 640, q = idx % 640;
    int tap = q >> 7, ic = q & 127;
    o[idx] = f2bf(c2w[(oc * 128 + ic) * 5 + tap]);
}

__global__ void k_w1pT(const float* __restrict__ w, ushort_t* __restrict__ o) {
    int idx = blockIdx.x * blockDim.x + threadIdx.x;
    if (idx >= 128 * 2816) return;
    int j = idx / 2816, c = idx % 2816;
    int tt = c >> 8, oc = c & 255;
    o[idx] = f2bf(w[(oc * 11 + tt) * 128 + j]);
}

// ---------------- lin2 + bn (lin1 bias + relu folded into load) ----------------
__global__ void k_lin2_bn(const float* __restrict__ x, const float* __restrict__ l1b,
                          const float* __restrict__ w,
                          const float* __restrict__ b, const float* __restrict__ g,
                          const float* __restrict__ bb, float* __restrict__ o) {
    int t = blockIdx.x * blockDim.x + threadIdx.x;
    int j = t & 31, bi = t >> 5;
    const float* xr = x + (long)bi * 128;
    float acc = b[j];
    for (int k = 0; k < 128; k++) acc += fmaxf(xr[k] + l1b[k], 0.f) * w[k * 32 + j];
    o[bi * 32 + j] = fmaxf(acc * g[j] + bb[j], 0.f);
}

// ---------------- final fused MLP ----------------
__global__ __launch_bounds__(256) void k_final(const float* __restrict__ hfin, const int* __restrict__ node,
                                               const float* __restrict__ dio, const float* __restrict__ dro,
                                               const float* __restrict__ pp,
                                               const float* __restrict__ fw, const float* __restrict__ fb,
                                               const float* __restrict__ f2w, const float* __restrict__ f2b,
                                               float* __restrict__ out) {
    __shared__ float w[64 * 32];
    __shared__ float w2[32];
    int t = threadIdx.x;
    for (int f = t; f < 2048; f += 256) w[f] = fw[f];
    if (t < 32) w2[t] = f2w[t];
    __syncthreads();
    int b = blockIdx.x * 256 + t;
    float p = *pp, q = 1.0f - p;
    float zin[64];
#pragma unroll
    for (int i = 0; i < 32; i++) zin[i] = hfin[b * 32 + i] * p;
    int n0 = node[b * 2], n1 = node[b * 2 + 1];
#pragma unroll
    for (int i = 0; i < 16; i++) zin[32 + i] = dio[n0 * 16 + i] * q;
#pragma unroll
    for (int i = 0; i < 16; i++) zin[48 + i] = dro[n1 * 16 + i] * q;
    float res = f2b[0];
    for (int j = 0; j < 32; j++) {
        float acc = fb[j];
#pragma unroll
        for (int i = 0; i < 64; i++) acc += zin[i] * w[i * 32 + j];
        res += fmaxf(acc, 0.f) * w2[j];
    }
    out[b] = res;
}

// ---------------- host ----------------
extern "C" void kernel_launch(void* const* d_in, const int* in_sizes, int n_in,
                              void* d_out, int out_size, void* d_ws, size_t ws_size,
                              hipStream_t stream) {
    const float* x        = (const float*)d_in[0];
    const int*   ei       = (const int*)d_in[1];
    const int*   node     = (const int*)d_in[3];
    const float* di_sim   = (const float*)d_in[4];
    const float* dr_sim   = (const float*)d_in[5];
    const float* drug_adj = (const float*)d_in[6];
    const float* dis_adj  = (const float*)d_in[7];
    const float* p        = (const float*)d_in[8];
    const float* W1 = (const float*)d_in[9],  *b1 = (const float*)d_in[10];
    const float* W2 = (const float*)d_in[11], *b2 = (const float*)d_in[12];
    const float* W3 = (const float*)d_in[13], *b3 = (const float*)d_in[14];
    const float* W4 = (const float*)d_in[15], *b4 = (const float*)d_in[16];
    const float* lin_di_w = (const float*)d_in[17], *lin_di_b = (const float*)d_in[18];
    const float* lin_dr_w = (const float*)d_in[19], *lin_dr_b = (const float*)d_in[20];
    const float* c1w = (const float*)d_in[21], *c1b = (const float*)d_in[22];
    const float* c2w = (const float*)d_in[23], *c2b = (const float*)d_in[24];
    const float* lin1w = (const float*)d_in[25], *lin1b = (const float*)d_in[26];
    const float* lin2w = (const float*)d_in[27], *lin2b = (const float*)d_in[28];
    const float* bng = (const float*)d_in[29], *bnb = (const float*)d_in[30];
    const float* fcsw = (const float*)d_in[31], *fcsb = (const float*)d_in[32];
    const float* fcs2w = (const float*)d_in[33], *fcs2b = (const float*)d_in[34];

    char* ws = (char*)d_ws;
    size_t o = 0;
    auto alloc = [&](size_t bytes) { size_t r = o; o += (bytes + 255) & ~(size_t)255; return r; };
    int*   csr     = (int*)(ws + alloc((size_t)NN * DCAP * 4));   // 31.5MB fixed-capacity rows
    float* dinvn   = (float*)(ws + alloc((size_t)NN * 4));
    float* hbuf    = (float*)(ws + alloc((size_t)NN * 32 * 4));  // reused: pool16 + bf16 staging
    float* cs      = (float*)(ws + alloc((size_t)NN * 64 * 4));  // later act2
    int*   sel     = (int*)(ws + alloc((size_t)NB * KSEL * 4));
    float* hfin    = (float*)(ws + alloc((size_t)NB * 32 * 4));
    ushort_t* w2colT = (ushort_t*)(ws + alloc((size_t)256 * 640 * 2));
    ushort_t* w1pT   = (ushort_t*)(ws + alloc((size_t)128 * 2816 * 2));
    float* ddin_di = (float*)(ws + alloc((size_t)NDRUG * 4));
    float* ddin_dr = (float*)(ws + alloc((size_t)NDIS * 4));
    float* dt2_di  = (float*)(ws + alloc((size_t)NDRUG * 16 * 4));
    float* dt2_dr  = (float*)(ws + alloc((size_t)NDIS * 16 * 4));
    float* do_di   = (float*)(ws + alloc((size_t)NDRUG * 16 * 4));
    float* do_dr   = (float*)(ws + alloc((size_t)NDIS * 16 * 4));
    size_t zbase = o;
    int*   degcnt  = (int*)(ws + alloc((size_t)NN * 4));          // zeroed each run
    float* lin1o   = (float*)(ws + alloc((size_t)NB * 128 * 4));
    float* de_di   = (float*)(ws + alloc((size_t)NDRUG * 256 * 4));   // atomic split-K target
    float* de_dr   = (float*)(ws + alloc((size_t)NDIS * 256 * 4));
    float* dt_di   = (float*)(ws + alloc((size_t)NDRUG * 64 * 4));
    float* dt_dr   = (float*)(ws + alloc((size_t)NDIS * 64 * 4));
    float* dg_di   = (float*)(ws + alloc((size_t)NDRUG * 64 * 4));
    float* dg_dr   = (float*)(ws + alloc((size_t)NDIS * 64 * 4));
    float* dg2_di  = (float*)(ws + alloc((size_t)NDRUG * 16 * 4));
    float* dg2_dr  = (float*)(ws + alloc((size_t)NDIS * 16 * 4));
    size_t zsize = o - zbase;
    ushort_t* pool16 = (ushort_t*)hbuf;   // first 15.7MB of hbuf after GCN done
    ushort_t* act2   = (ushort_t*)cs;     // alias after conv1 done
    // bf16 staging in the free tail of hbuf
    char* hb = (char*)hbuf;
    ushort_t* di_sim16 = (ushort_t*)(hb + 15728640);   // 2MB; reused as drugadj16 after de_mfma
    ushort_t* dr_sim16 = (ushort_t*)(hb + 17825792);   // 8MB; reused as disadj16 after de_mfma
    ushort_t* lindiT16 = (ushort_t*)(hb + 26214400);
    ushort_t* lindrT16 = (ushort_t*)(hb + 26738688);
    ushort_t* c1w16    = (ushort_t*)(hb + 27787264);   // 16KB
    ushort_t* uT16_di  = (ushort_t*)(hb + 27811840);   // 128KB
    ushort_t* uT16_dr  = (ushort_t*)(hb + 27942912);   // 256KB
    ushort_t* drugadj16 = di_sim16;
    ushort_t* disadj16  = dr_sim16;

    hipMemsetAsync(ws + zbase, 0, zsize, stream);

    // CSR build: single-pass direct scatter
    k_edge_scatter<<<2048, 256, 0, stream>>>(ei, degcnt, csr);
    k_dinv<<<(NN + 255) / 256, 256, 0, stream>>>(degcnt, dinvn);

    // GCN (fp32 — preserves stable sort keys)
    k_xw<<<NN / 64, 256, 0, stream>>>(x, W1, hbuf, 64, 64);
    k_gcn_agg<<<NN / 32, 256, 0, stream>>>(hbuf, csr, degcnt, dinvn, b1, cs, 0);
    k_xw<<<NN / 64, 256, 0, stream>>>(cs, W2, hbuf, 32, 64);
    k_gcn_agg<<<NN / 32, 256, 0, stream>>>(hbuf, csr, degcnt, dinvn, b2, cs, 32);

    k_select<<<NB / 4, 256, 0, stream>>>(cs, sel);

    // dense-path front: convert (L2-warm) then de MFMA (split-K for occupancy)
    k_cvt2<<<5120, 256, 0, stream>>>(di_sim, di_sim16, (long)NDRUG * NDRUG,
                                     dr_sim, dr_sim16, (long)NDIS * NDIS);
    k_linwT2<<<dim3(48, 4), 256, 0, stream>>>(lin_di_w, lindiT16, NDRUG,
                                              lin_dr_w, lindrT16, NDIS);
    k_de_mfma<<<dim3(16, 4, 12), 256, 0, stream>>>(
        di_sim16, lindiT16, de_di, lin_di_b, NDRUG, NDRUG, 4,
        dr_sim16, lindrT16, de_dr, lin_dr_b, NDIS, NDIS, 8);
    k_dense_deg2<<<(NDRUG + NDIS) * 64 / 256, 256, 0, stream>>>(drug_adj, ddin_di, NDRUG, dis_adj, ddin_dr, NDIS);
    // adj -> bf16 (reuses sim16 slots; stream-ordered after de_mfma)
    k_cvt2<<<5120, 256, 0, stream>>>(drug_adj, drugadj16, (long)NDRUG * NDRUG,
                                     dis_adj, disadj16, (long)NDIS * NDIS);

    // weight prep
    k_cvt2<<<8, 256, 0, stream>>>(c1w, c1w16, 8192, c1w, c1w16, 0);
    k_w2colT<<<(256 * 640 + 255) / 256, 256, 0, stream>>>(c2w, w2colT);
    k_w1pT<<<(128 * 2816 + 255) / 256, 256, 0, stream>>>(lin1w, w1pT);

    // conv1 via MFMA (gather + relu + pool fused, coalesced flush) -> pool16
    k_conv1_mfma<<<960, 256, 0, stream>>>(cs, sel, c1w16, c1b, pool16);

    // conv2: bf16 MFMA -> act2 bf16 (aliases cs), coalesced C flush
    k_conv2_mfma<<<dim3(352, 2), 256, 0, stream>>>(pool16, w2colT, act2, c2b);

    // lin1: bf16 MFMA split-K -> lin1o fp32 (zeroed)
    k_lin1_mfma<<<dim3(32, 1, 4), 256, 0, stream>>>(act2, w1pT, lin1o);
    k_lin2_bn<<<NB * 32 / 256, 256, 0, stream>>>(lin1o, lin1b, lin2w, lin2b, bng, bnb, hfin);

    // ---- dense drug (p0) + disease (p1) back half ----
    // u = dinv * (de @ W3)   [bias already in de]
    k_gemm_sk<<<dim3(NDIS / 64, 1, 8), 256, 0, stream>>>(
        de_di, W3, dt_di, nullptr, ddin_di, NDRUG, 64, 256, 256, 4, 64,
        de_dr, W3, dt_dr, nullptr, ddin_dr, NDIS, 64, 256, 256, 4, 64);
    // uT bf16 for g-stage
    k_uT2<<<48, 256, 0, stream>>>(dt_di, uT16_di, NDRUG, dt_dr, uT16_dr, NDIS);
    // g = adj @ u via bf16 MFMA (zero-inited dg)
    k_g_mfma<<<dim3(16, 1, 24), 256, 0, stream>>>(
        drugadj16, uT16_di, dg_di, NDRUG, NDRUG, 8,
        disadj16, uT16_dr, dg_dr, NDIS, NDIS, 16);
    k_fix_w4<<<(NDRUG + NDIS) / 16, 256, 0, stream>>>(
        dg_di, dt_di, drug_adj, ddin_di, dt2_di, NDRUG,
        dg_dr, dt_dr, dis_adj, ddin_dr, dt2_dr, NDIS, b3, W4);
    k_adj16<<<dim3(NDIS / 16, 1, 6), 256, 0, stream>>>(
        drug_adj, dt2_di, dg2_di, NDRUG, 2, 512,
        dis_adj, dt2_dr, dg2_dr, NDIS, 4, 512);
    k_fixup2<<<((NDRUG + NDIS) * 16 + 255) / 256, 256, 0, stream>>>(
        dg2_di, dt2_di, drug_adj, ddin_di, do_di, NDRUG,
        dg2_dr, dt2_dr, dis_adj, ddin_dr, do_dr, NDIS, b4, 16);

    k_final<<<NB / 256, 256, 0, stream>>>(hfin, node, do_di, do_dr, p, fcsw, fcsb, fcs2w, fcs2b, (float*)d_out);
}

// Round 25
// 444.893 us; speedup vs baseline: 1.1641x; 1.1641x over previous
//
#include <hip/hip_runtime.h>

#define NN 245760
#define NB 4096
#define NPER 60
#define NE 2000000
#define KSEL 30
#define NDRUG 1024
#define NDIS 2048
#define NBKT 480          // buckets of 512 nodes (NN = 480*512)
#define CHUNK 8192
#define SEGCAP 4992       // max edges per bucket (mean 4167, +12 sigma)

typedef unsigned short ushort_t;
typedef unsigned int uint_t;
using bf16x8 = __attribute__((ext_vector_type(8))) short;
using f32x4 = __attribute__((ext_vector_type(4))) float;

__device__ inline ushort_t f2bf(float f) {
    union { float f; unsigned int u; } v; v.f = f;
    unsigned int r = v.u + 0x7FFF + ((v.u >> 16) & 1);
    return (ushort_t)(r >> 16);
}

// ---------------- CSR build: fixed-stride buckets, 4-batched edge loads ----------------
__global__ __launch_bounds__(256) void k_bscatter(const int* __restrict__ ei,
                                                  int* __restrict__ bfill,
                                                  uint_t* __restrict__ pairs) {
    __shared__ int hist[NBKT], fill[NBKT], gbase[NBKT];
    int t = threadIdx.x;
    long e0 = (long)blockIdx.x * CHUNK;
    int cnt = (int)min((long)CHUNK, (long)NE - e0);
    for (int i = t; i < NBKT; i += 256) { hist[i] = 0; fill[i] = 0; }
    __syncthreads();
    // pass 1: histogram (4 loads in flight per thread)
    for (int i = t; i < cnt; i += 1024) {
        int d[4]; int hv[4];
#pragma unroll
        for (int j = 0; j < 4; j++) {
            int ii = i + j * 256;
            hv[j] = ii < cnt;
            d[j] = hv[j] ? ei[NE + e0 + ii] : 0;
        }
#pragma unroll
        for (int j = 0; j < 4; j++)
            if (hv[j]) atomicAdd(&hist[d[j] >> 9], 1);
    }
    __syncthreads();
    for (int i = t; i < NBKT; i += 256)
        if (hist[i]) gbase[i] = i * SEGCAP + atomicAdd(&bfill[i], hist[i]);
    __syncthreads();
    // pass 2: scatter (4 edge pairs in flight per thread)
    for (int i = t; i < cnt; i += 1024) {
        int s[4], d[4]; int hv[4];
#pragma unroll
        for (int j = 0; j < 4; j++) {
            int ii = i + j * 256;
            hv[j] = ii < cnt;
            if (hv[j]) { s[j] = ei[e0 + ii]; d[j] = ei[NE + e0 + ii]; }
        }
#pragma unroll
        for (int j = 0; j < 4; j++) {
            if (hv[j]) {
                int b = d[j] >> 9;
                int pos = gbase[b] + atomicAdd(&fill[b], 1);
                if (pos < (b + 1) * SEGCAP)
                    pairs[pos] = ((uint_t)s[j] << 9) | (uint_t)(d[j] & 511);
            }
        }
    }
}

__global__ __launch_bounds__(256) void k_bbuild(const uint_t* __restrict__ pairs,
                                                const int* __restrict__ bfill,
                                                int* __restrict__ csr,
                                                int* __restrict__ rowp,
                                                int* __restrict__ cntg,
                                                float* __restrict__ dinv) {
    __shared__ int hist[512], nbase[512], nfill[512], scanA[512], scanB[512];
    __shared__ int seg[SEGCAP];
    int t = threadIdx.x, b = blockIdx.x;
    int ebase = b * SEGCAP;
    int ecnt = bfill[b];
    if (ecnt > SEGCAP) ecnt = SEGCAP;
    for (int i = t; i < 512; i += 256) { hist[i] = 0; nfill[i] = 0; }
    __syncthreads();
    for (int i = t; i < ecnt; i += 256)
        atomicAdd(&hist[pairs[ebase + i] & 511], 1);
    __syncthreads();
    for (int i = t; i < 512; i += 256) scanA[i] = hist[i];
    __syncthreads();
    int* src = scanA; int* dst = scanB;
    for (int off = 1; off < 512; off <<= 1) {
        for (int i = t; i < 512; i += 256)
            dst[i] = src[i] + ((i >= off) ? src[i - off] : 0);
        __syncthreads();
        int* tmp = src; src = dst; dst = tmp;
    }
    for (int i = t; i < 512; i += 256) {
        int h = hist[i];
        int excl = src[i] - h;
        nbase[i] = excl;
        int n = (b << 9) + i;
        rowp[n] = ebase + excl;
        cntg[n] = h;
        dinv[n] = 1.0f / sqrtf((float)h + 1.0f);
    }
    __syncthreads();
    for (int i = t; i < ecnt; i += 256) {
        uint_t v = pairs[ebase + i];
        int ln = v & 511;
        int pos = nbase[ln] + atomicAdd(&nfill[ln], 1);
        if (pos < SEGCAP) seg[pos] = (int)(v >> 9);
    }
    __syncthreads();
    for (int i = t; i < ecnt; i += 256) csr[ebase + i] = seg[i];
}

// ---------------- X(M x K, stride lda) @ W(K x 32) -> h(M x 32), K<=64 ----------------
__global__ __launch_bounds__(256) void k_xw(const float* __restrict__ A, const float* __restrict__ W,
                                            float* __restrict__ h, int K, int lda) {
    __shared__ float Xs[64][65];
    __shared__ float Ws[64][32];
    int t = threadIdx.x;
    int r0 = blockIdx.x * 64;
    int kq = K >> 2;
    for (int idx = t; idx < 64 * kq; idx += 256) {
        int row = idx / kq, q = idx % kq;
        float4 v = *(const float4*)(A + (long)(r0 + row) * lda + q * 4);
        Xs[row][q * 4 + 0] = v.x; Xs[row][q * 4 + 1] = v.y;
        Xs[row][q * 4 + 2] = v.z; Xs[row][q * 4 + 3] = v.w;
    }
    for (int idx = t; idx < K * 32; idx += 256) ((float*)Ws)[idx] = W[idx];
    __syncthreads();
    int r = (t >> 3) * 2, c = (t & 7) * 4;
    float4 acc0 = {0, 0, 0, 0}, acc1 = {0, 0, 0, 0};
    for (int k = 0; k < K; k++) {
        float x0 = Xs[r][k], x1 = Xs[r + 1][k];
        float4 w = *(const float4*)&Ws[k][c];
        acc0.x += x0 * w.x; acc0.y += x0 * w.y; acc0.z += x0 * w.z; acc0.w += x0 * w.w;
        acc1.x += x1 * w.x; acc1.y += x1 * w.y; acc1.z += x1 * w.z; acc1.w += x1 * w.w;
    }
    *(float4*)(h + (long)(r0 + r) * 32 + c) = acc0;
    *(float4*)(h + (long)(r0 + r + 1) * 32 + c) = acc1;
}

// ---------------- GCN aggregation: batched-edge gather (8 loads in flight per group) ----------------
__global__ void k_gcn_agg(const float* __restrict__ h, const int* __restrict__ csr,
                          const int* __restrict__ rowp, const int* __restrict__ cnt,
                          const float* __restrict__ dinv, const float* __restrict__ bias,
                          float* __restrict__ out, int colofs) {
    int t = threadIdx.x;
    int l = t & 7, g = t >> 3;
    int wl = t & 63;                 // lane within wave
    int gbase = wl & ~7;             // first lane of this 8-lane group
    int d = blockIdx.x * 32 + g;
    float dd = dinv[d];
    int start = rowp[d], c = cnt[d];
    float4 hv = *(const float4*)(h + (long)d * 32 + l * 4);
    float4 acc; acc.x = dd * hv.x; acc.y = dd * hv.y; acc.z = dd * hv.z; acc.w = dd * hv.w;
    int k = 0;
    while (k < c) {
        int nb = c - k; if (nb > 8) nb = 8;
        int sl = (l < nb) ? csr[start + k + l] : 0;
        int sj[8]; float ds[8]; float4 hj[8];
#pragma unroll
        for (int j = 0; j < 8; j++)
            sj[j] = __shfl(sl, gbase + j, 64);
#pragma unroll
        for (int j = 0; j < 8; j++)
            if (j < nb) ds[j] = dinv[sj[j]];
#pragma unroll
        for (int j = 0; j < 8; j++)
            if (j < nb) hj[j] = *(const float4*)(h + (long)sj[j] * 32 + l * 4);
#pragma unroll
        for (int j = 0; j < 8; j++) {
            if (j < nb) {
                acc.x += ds[j] * hj[j].x;
                acc.y += ds[j] * hj[j].y;
                acc.z += ds[j] * hj[j].z;
                acc.w += ds[j] * hj[j].w;
            }
        }
        k += nb;
    }
    float4 bv = *(const float4*)(bias + l * 4);
    float* op = out + (long)d * 64 + colofs + l * 4;
    op[0] = fmaxf(dd * acc.x + bv.x, 0.f);
    op[1] = fmaxf(dd * acc.y + bv.y, 0.f);
    op[2] = fmaxf(dd * acc.z + bv.z, 0.f);
    op[3] = fmaxf(dd * acc.w + bv.w, 0.f);
}

// ---------------- conv1 via bf16 MFMA: gather + relu + pool, LDS-staged coalesced flush ----------------
__global__ __launch_bounds__(256, 2) void k_conv1_mfma(const float* __restrict__ cs,
                                                       const int* __restrict__ sel,
                                                       const ushort_t* __restrict__ c1w16,
                                                       const float* __restrict__ c1b,
                                                       ushort_t* __restrict__ po16) {
    __shared__ ushort_t A_lds[128 * 72];
    __shared__ ushort_t B_lds[128 * 72];
    int t = threadIdx.x;
    int r0 = blockIdx.x * 128;
#pragma unroll
    for (int rnd = 0; rnd < 4; rnd++) {
        int idx = t + rnd * 256;
        int row = idx >> 3, seg = idx & 7;
        const float* src = cs + (long)sel[r0 + row] * 64 + seg * 8;
        float4 v0 = *(const float4*)src;
        float4 v1 = *(const float4*)(src + 4);
        ushort_t tmp[8] = {f2bf(v0.x), f2bf(v0.y), f2bf(v0.z), f2bf(v0.w),
                           f2bf(v1.x), f2bf(v1.y), f2bf(v1.z), f2bf(v1.w)};
        *(uint4*)&A_lds[row * 72 + seg * 8] = *(uint4*)tmp;
        *(uint4*)&B_lds[row * 72 + seg * 8] = *(const uint4*)(c1w16 + row * 64 + seg * 8);
    }
    __syncthreads();
    int wv = t >> 6, lane = t & 63;
    int wm = wv >> 1, wn = wv & 1;
    int lrow = lane & 15, lk = (lane >> 4) * 8, lr4 = (lane >> 4) * 4;
    f32x4 acc[4][4] = {};
#pragma unroll
    for (int kk = 0; kk < 2; kk++) {
        bf16x8 a[4], b[4];
#pragma unroll
        for (int f = 0; f < 4; f++) {
            a[f] = *(const bf16x8*)&A_lds[(wm * 64 + f * 16 + lrow) * 72 + kk * 32 + lk];
            b[f] = *(const bf16x8*)&B_lds[(wn * 64 + f * 16 + lrow) * 72 + kk * 32 + lk];
        }
#pragma unroll
        for (int i = 0; i < 4; i++)
#pragma unroll
            for (int j = 0; j < 4; j++)
                acc[i][j] = __builtin_amdgcn_mfma_f32_16x16x32_bf16(a[i], b[j], acc[i][j], 0, 0, 0);
    }
    __syncthreads();                       // MFMA operands consumed; reuse A_lds for pooled tile
    ushort_t* po_lds = A_lds;              // 64 x 128 ushorts = 8192 <= 9216
#pragma unroll
    for (int fn = 0; fn < 4; fn++) {
        int col = wn * 64 + fn * 16 + lrow;
        float bb = c1b[col];
#pragma unroll
        for (int fm = 0; fm < 4; fm++) {
            int lrow2 = wm * 32 + fm * 8 + (lr4 >> 1);   // even
            float v0 = fmaxf(acc[fm][fn][0] + bb, 0.f);
            float v1 = fmaxf(acc[fm][fn][1] + bb, 0.f);
            float v2 = fmaxf(acc[fm][fn][2] + bb, 0.f);
            float v3 = fmaxf(acc[fm][fn][3] + bb, 0.f);
            po_lds[lrow2 * 128 + col]       = f2bf(fmaxf(v0, v1));
            po_lds[(lrow2 + 1) * 128 + col] = f2bf(fmaxf(v2, v3));
        }
    }
    __syncthreads();
    uint4* dst = (uint4*)(po16 + (long)(r0 >> 1) * 128);
    const uint4* srcp = (const uint4*)po_lds;
#pragma unroll
    for (int i = 0; i < 4; i++) dst[t + i * 256] = srcp[t + i * 256];
}

// ---------------- conv2: bf16 MFMA im2col GEMM (direct LDS staging, LDS-staged C flush) ----------------
__global__ __launch_bounds__(256, 2) void k_conv2_mfma(const ushort_t* __restrict__ pool16,
                                                       const ushort_t* __restrict__ w2colT,
                                                       ushort_t* __restrict__ act2,
                                                       const float* __restrict__ bias) {
    __shared__ ushort_t smem[2 * 128 * 72];   // A | B ; reused as 128x128 C-tile
    ushort_t* A_lds = smem;
    ushort_t* B_lds = smem + 128 * 72;
    int t = threadIdx.x;
    int r0 = blockIdx.x * 128, c0 = blockIdx.y * 128;
    long abase[4]; const ushort_t* bptr[4]; int lofs[4];
#pragma unroll
    for (int rnd = 0; rnd < 4; rnd++) {
        int idx = t + rnd * 256;
        int row = idx >> 3, seg = idx & 7;
        int arow = r0 + row;
        int bb = arow / 11, tt2 = arow - bb * 11;
        abase[rnd] = (long)(bb * 15 + tt2) * 128 + seg * 8;
        bptr[rnd] = w2colT + (long)(c0 + row) * 640 + seg * 8;
        lofs[rnd] = row * 72 + seg * 8;
    }
    int wv = t >> 6, lane = t & 63;
    int wm = wv >> 1, wn = wv & 1;
    int lrow = lane & 15, lk = (lane >> 4) * 8, lr4 = (lane >> 4) * 4;
    f32x4 acc[4][4] = {};
    for (int k0 = 0; k0 < 640; k0 += 64) {
#pragma unroll
        for (int rnd = 0; rnd < 4; rnd++) {
            *(uint4*)&A_lds[lofs[rnd]] = *(const uint4*)(pool16 + abase[rnd] + k0);
            *(uint4*)&B_lds[lofs[rnd]] = *(const uint4*)(bptr[rnd] + k0);
        }
        __syncthreads();
#pragma unroll
        for (int kk = 0; kk < 2; kk++) {
            bf16x8 a[4], b[4];
#pragma unroll
            for (int f = 0; f < 4; f++) {
                a[f] = *(const bf16x8*)&A_lds[(wm * 64 + f * 16 + lrow) * 72 + kk * 32 + lk];
                b[f] = *(const bf16x8*)&B_lds[(wn * 64 + f * 16 + lrow) * 72 + kk * 32 + lk];
            }
#pragma unroll
            for (int i = 0; i < 4; i++)
#pragma unroll
                for (int j = 0; j < 4; j++)
                    acc[i][j] = __builtin_amdgcn_mfma_f32_16x16x32_bf16(a[i], b[j], acc[i][j], 0, 0, 0);
        }
        __syncthreads();
    }
    // stage C-tile (128x128 bf16) in LDS, flush coalesced
    ushort_t* c_lds = smem;
#pragma unroll
    for (int fn = 0; fn < 4; fn++) {
        int col = wn * 64 + fn * 16 + lrow;
        float bv = bias[c0 + col];
#pragma unroll
        for (int fm = 0; fm < 4; fm++) {
            int lr = wm * 64 + fm * 16 + lr4;
#pragma unroll
            for (int j = 0; j < 4; j++)
                c_lds[(lr + j) * 128 + col] = f2bf(fmaxf(acc[fm][fn][j] + bv, 0.f));
        }
    }
    __syncthreads();
#pragma unroll
    for (int i = 0; i < 8; i++) {
        int idx = t + i * 256;          // 0..2047
        int row = idx >> 4, q = idx & 15;
        *(uint4*)(act2 + (long)(r0 + row) * 256 + c0 + q * 8) = ((const uint4*)c_lds)[idx];
    }
}

// ---------------- lin1: bf16 MFMA split-K, fp32 atomic epilogue (direct LDS staging) ----------------
__global__ __launch_bounds__(256, 2) void k_lin1_mfma(const ushort_t* __restrict__ A,
                                                      const ushort_t* __restrict__ Bm,
                                                      float* __restrict__ C) {
    __shared__ ushort_t A_lds[128 * 72];
    __shared__ ushort_t B_lds[128 * 72];
    int t = threadIdx.x;
    int r0 = blockIdx.x * 128;
    int kz = blockIdx.z;
    const ushort_t* ap[4]; const ushort_t* bp[4]; int lofs[4];
#pragma unroll
    for (int rnd = 0; rnd < 4; rnd++) {
        int idx = t + rnd * 256;
        int row = idx >> 3, seg = idx & 7;
        ap[rnd] = A + (long)(r0 + row) * 2816 + kz * 704 + seg * 8;
        bp[rnd] = Bm + (long)row * 2816 + kz * 704 + seg * 8;
        lofs[rnd] = row * 72 + seg * 8;
    }
    int wv = t >> 6, lane = t & 63;
    int wm = wv >> 1, wn = wv & 1;
    int lrow = lane & 15, lk = (lane >> 4) * 8, lr4 = (lane >> 4) * 4;
    f32x4 acc[4][4] = {};
    for (int k0 = 0; k0 < 704; k0 += 64) {
#pragma unroll
        for (int rnd = 0; rnd < 4; rnd++) {
            *(uint4*)&A_lds[lofs[rnd]] = *(const uint4*)(ap[rnd] + k0);
            *(uint4*)&B_lds[lofs[rnd]] = *(const uint4*)(bp[rnd] + k0);
        }
        __syncthreads();
#pragma unroll
        for (int kk = 0; kk < 2; kk++) {
            bf16x8 a[4], b[4];
#pragma unroll
            for (int f = 0; f < 4; f++) {
                a[f] = *(const bf16x8*)&A_lds[(wm * 64 + f * 16 + lrow) * 72 + kk * 32 + lk];
                b[f] = *(const bf16x8*)&B_lds[(wn * 64 + f * 16 + lrow) * 72 + kk * 32 + lk];
            }
#pragma unroll
            for (int i = 0; i < 4; i++)
#pragma unroll
                for (int j = 0; j < 4; j++)
                    acc[i][j] = __builtin_amdgcn_mfma_f32_16x16x32_bf16(a[i], b[j], acc[i][j], 0, 0, 0);
        }
        __syncthreads();
    }
#pragma unroll
    for (int fn = 0; fn < 4; fn++) {
        int col = wn * 64 + fn * 16 + lrow;
#pragma unroll
        for (int fm = 0; fm < 4; fm++) {
            int rowb = r0 + wm * 64 + fm * 16 + lr4;
#pragma unroll
            for (int j = 0; j < 4; j++)
                atomicAdd(&C[(long)(rowb + j) * 128 + col], acc[fm][fn][j]);
        }
    }
}

// ---------------- de = sim @ lin_w + b : bf16 MFMA, split-K, atomic fp32 epilogue ----------------
__global__ __launch_bounds__(256, 2) void k_de_mfma(
    const ushort_t* __restrict__ A0, const ushort_t* __restrict__ B0, float* __restrict__ C0,
    const float* __restrict__ bias0, int M0, int K0, int KS0,
    const ushort_t* __restrict__ A1, const ushort_t* __restrict__ B1, float* __restrict__ C1,
    const float* __restrict__ bias1, int M1, int K1, int KS1) {
    __shared__ ushort_t A_lds[128 * 72];
    __shared__ ushort_t B_lds[64 * 72];
    int z = blockIdx.z;
    const ushort_t* A; const ushort_t* Bm; float* C; const float* bias; int M, K, kz, KS;
    if (z < KS0) { A = A0; Bm = B0; C = C0; bias = bias0; M = M0; K = K0; kz = z; KS = KS0; }
    else { A = A1; Bm = B1; C = C1; bias = bias1; M = M1; K = K1; kz = z - KS0; KS = KS1; }
    int r0 = blockIdx.x * 128, c0 = blockIdx.y * 64;
    if (r0 >= M) return;
    int Kc = K / KS;
    int kb = kz * Kc;
    int t = threadIdx.x;
    const ushort_t* ap[4]; int alofs[4];
#pragma unroll
    for (int rnd = 0; rnd < 4; rnd++) {
        int idx = t + rnd * 256;
        int row = idx >> 3, seg = idx & 7;
        ap[rnd] = A + (long)(r0 + row) * K + kb + seg * 8;
        alofs[rnd] = row * 72 + seg * 8;
    }
    const ushort_t* bp[2]; int blofs[2];
#pragma unroll
    for (int rnd = 0; rnd < 2; rnd++) {
        int idx = t + rnd * 256;
        int row = idx >> 3, seg = idx & 7;
        bp[rnd] = Bm + (long)(c0 + row) * K + kb + seg * 8;
        blofs[rnd] = row * 72 + seg * 8;
    }
    int wv = t >> 6, lane = t & 63;
    int lrow = lane & 15, lk = (lane >> 4) * 8, lr4 = (lane >> 4) * 4;
    uint4 areg[4], breg[2];
#pragma unroll
    for (int rnd = 0; rnd < 4; rnd++) areg[rnd] = *(const uint4*)(ap[rnd]);
#pragma unroll
    for (int rnd = 0; rnd < 2; rnd++) breg[rnd] = *(const uint4*)(bp[rnd]);
    f32x4 acc[2][4] = {};
    for (int k0 = 0; k0 < Kc; k0 += 64) {
#pragma unroll
        for (int rnd = 0; rnd < 4; rnd++) *(uint4*)&A_lds[alofs[rnd]] = areg[rnd];
#pragma unroll
        for (int rnd = 0; rnd < 2; rnd++) *(uint4*)&B_lds[blofs[rnd]] = breg[rnd];
        __syncthreads();
        if (k0 + 64 < Kc) {
#pragma unroll
            for (int rnd = 0; rnd < 4; rnd++) areg[rnd] = *(const uint4*)(ap[rnd] + k0 + 64);
#pragma unroll
            for (int rnd = 0; rnd < 2; rnd++) breg[rnd] = *(const uint4*)(bp[rnd] + k0 + 64);
        }
#pragma unroll
        for (int kk = 0; kk < 2; kk++) {
            bf16x8 a[2], b[4];
#pragma unroll
            for (int f = 0; f < 2; f++)
                a[f] = *(const bf16x8*)&A_lds[(wv * 32 + f * 16 + lrow) * 72 + kk * 32 + lk];
#pragma unroll
            for (int f = 0; f < 4; f++)
                b[f] = *(const bf16x8*)&B_lds[(f * 16 + lrow) * 72 + kk * 32 + lk];
#pragma unroll
            for (int i = 0; i < 2; i++)
#pragma unroll
                for (int j = 0; j < 4; j++)
                    acc[i][j] = __builtin_amdgcn_mfma_f32_16x16x32_bf16(a[i], b[j], acc[i][j], 0, 0, 0);
        }
        __syncthreads();
    }
#pragma unroll
    for (int fn = 0; fn < 4; fn++) {
        int col = c0 + fn * 16 + lrow;
        float bv = (kz == 0) ? bias[col] : 0.f;
#pragma unroll
        for (int fm = 0; fm < 2; fm++) {
            int rowb = r0 + wv * 32 + fm * 16 + lr4;
#pragma unroll
            for (int j = 0; j < 4; j++)
                atomicAdd(&C[(long)(rowb + j) * 256 + col], acc[fm][fn][j] + bv);
        }
    }
}

// ---------------- g = adj @ u : bf16 MFMA, N=64, split-K, atomic fp32 epilogue ----------------
__global__ __launch_bounds__(256, 2) void k_g_mfma(
    const ushort_t* __restrict__ A0, const ushort_t* __restrict__ B0, float* __restrict__ C0,
    int M0, int K0, int KS0,
    const ushort_t* __restrict__ A1, const ushort_t* __restrict__ B1, float* __restrict__ C1,
    int M1, int K1, int KS1) {
    __shared__ ushort_t A_lds[128 * 72];
    __shared__ ushort_t B_lds[64 * 72];
    int z = blockIdx.z;
    const ushort_t* A; const ushort_t* Bm; float* C; int M, K, kz, KS;
    if (z < KS0) { A = A0; Bm = B0; C = C0; M = M0; K = K0; kz = z; KS = KS0; }
    else { A = A1; Bm = B1; C = C1; M = M1; K = K1; kz = z - KS0; KS = KS1; }
    int r0 = blockIdx.x * 128;
    if (r0 >= M) return;
    int Kc = K / KS;
    int kb = kz * Kc;
    int t = threadIdx.x;
    const ushort_t* ap[4]; int alofs[4];
#pragma unroll
    for (int rnd = 0; rnd < 4; rnd++) {
        int idx = t + rnd * 256;
        int row = idx >> 3, seg = idx & 7;
        ap[rnd] = A + (long)(r0 + row) * K + kb + seg * 8;
        alofs[rnd] = row * 72 + seg * 8;
    }
    const ushort_t* bp[2]; int blofs[2];
#pragma unroll
    for (int rnd = 0; rnd < 2; rnd++) {
        int idx = t + rnd * 256;
        int row = idx >> 3, seg = idx & 7;
        bp[rnd] = Bm + (long)row * K + kb + seg * 8;
        blofs[rnd] = row * 72 + seg * 8;
    }
    int wv = t >> 6, lane = t & 63;
    int lrow = lane & 15, lk = (lane >> 4) * 8, lr4 = (lane >> 4) * 4;
    uint4 areg[4], breg[2];
#pragma unroll
    for (int rnd = 0; rnd < 4; rnd++) areg[rnd] = *(const uint4*)(ap[rnd]);
#pragma unroll
    for (int rnd = 0; rnd < 2; rnd++) breg[rnd] = *(const uint4*)(bp[rnd]);
    f32x4 acc[2][4] = {};
    for (int k0 = 0; k0 < Kc; k0 += 64) {
#pragma unroll
        for (int rnd = 0; rnd < 4; rnd++) *(uint4*)&A_lds[alofs[rnd]] = areg[rnd];
#pragma unroll
        for (int rnd = 0; rnd < 2; rnd++) *(uint4*)&B_lds[blofs[rnd]] = breg[rnd];
        __syncthreads();
        if (k0 + 64 < Kc) {
#pragma unroll
            for (int rnd = 0; rnd < 4; rnd++) areg[rnd] = *(const uint4*)(ap[rnd] + k0 + 64);
#pragma unroll
            for (int rnd = 0; rnd < 2; rnd++) breg[rnd] = *(const uint4*)(bp[rnd] + k0 + 64);
        }
#pragma unroll
        for (int kk = 0; kk < 2; kk++) {
            bf16x8 a[2], b[4];
#pragma unroll
            for (int f = 0; f < 2; f++)
                a[f] = *(const bf16x8*)&A_lds[(wv * 32 + f * 16 + lrow) * 72 + kk * 32 + lk];
#pragma unroll
            for (int f = 0; f < 4; f++)
                b[f] = *(const bf16x8*)&B_lds[(f * 16 + lrow) * 72 + kk * 32 + lk];
#pragma unroll
            for (int i = 0; i < 2; i++)
#pragma unroll
                for (int j = 0; j < 4; j++)
                    acc[i][j] = __builtin_amdgcn_mfma_f32_16x16x32_bf16(a[i], b[j], acc[i][j], 0, 0, 0);
        }
        __syncthreads();
    }
#pragma unroll
    for (int fn = 0; fn < 4; fn++) {
        int col = fn * 16 + lrow;
#pragma unroll
        for (int fm = 0; fm < 2; fm++) {
            int rowb = r0 + wv * 32 + fm * 16 + lr4;
#pragma unroll
            for (int j = 0; j < 4; j++)
                atomicAdd(&C[(long)(rowb + j) * 64 + col], acc[fm][fn][j]);
        }
    }
}

// ---------------- conversions ----------------
__global__ void k_cvt2(const float* __restrict__ a0, ushort_t* __restrict__ o0, long n0,
                       const float* __restrict__ a1, ushort_t* __restrict__ o1, long n1) {
    long i4 = ((long)blockIdx.x * 256 + threadIdx.x) * 4;
    const float* a; ushort_t* o;
    if (i4 < n0) { a = a0 + i4; o = o0 + i4; }
    else {
        long j = i4 - n0;
        if (j >= n1) return;
        a = a1 + j; o = o1 + j;
    }
    float4 v = *(const float4*)a;
    o[0] = f2bf(v.x); o[1] = f2bf(v.y); o[2] = f2bf(v.z); o[3] = f2bf(v.w);
}

// lin_w (K x 256) -> bf16 transposed [n][k]; LDS tile transpose, dual problem
__global__ void k_linwT2(const float* __restrict__ w0, ushort_t* __restrict__ o0, int K0,
                         const float* __restrict__ w1, ushort_t* __restrict__ o1, int K1) {
    __shared__ float tile[64][65];
    int nb0 = K0 / 64;
    int bx = blockIdx.x;
    const float* w; ushort_t* o; int K, kt;
    if (bx < nb0) { w = w0; o = o0; K = K0; kt = bx; }
    else { w = w1; o = o1; K = K1; kt = bx - nb0; }
    int n0 = blockIdx.y * 64, k0 = kt * 64;
    int t = threadIdx.x;
    int r = t >> 6, c = t & 63;
    for (int rr = r; rr < 64; rr += 4)
        tile[rr][c] = w[(long)(k0 + rr) * 256 + n0 + c];
    __syncthreads();
    for (int rr = r; rr < 64; rr += 4)
        o[(long)(n0 + rr) * K + k0 + c] = f2bf(tile[c][rr]);
}

// u (K x 64) -> uT bf16 [64][K]; dual problem
__global__ void k_uT2(const float* __restrict__ u0, ushort_t* __restrict__ o0, int K0,
                      const float* __restrict__ u1, ushort_t* __restrict__ o1, int K1) {
    __shared__ float tile[64][65];
    int nb0 = K0 / 64;
    int bx = blockIdx.x;
    const float* u; ushort_t* o; int K, kt;
    if (bx < nb0) { u = u0; o = o0; K = K0; kt = bx; }
    else { u = u1; o = o1; K = K1; kt = bx - nb0; }
    int k0 = kt * 64;
    int t = threadIdx.x;
    int r = t >> 6, c = t & 63;
    for (int rr = r; rr < 64; rr += 4)
        tile[rr][c] = u[(long)(k0 + rr) * 64 + c];
    __syncthreads();
    for (int rr = r; rr < 64; rr += 4)
        o[(long)rr * K + k0 + c] = f2bf(tile[c][rr]);
}

// ---------------- dual-problem split-K 64x64 GEMM (fp32, register-prefetched K-loop) ----------------
__global__ __launch_bounds__(256) void k_gemm_sk(
    const float* A0, const float* B0, float* C0, const float* ab0p, const float* cs0p,
    int M0, int N0, int K0, int lda0, int KS0, int Kc0,
    const float* A1, const float* B1, float* C1, const float* ab1p, const float* cs1p,
    int M1, int N1, int K1, int lda1, int KS1, int Kc1) {
    int z = blockIdx.z;
    const float* A; const float* Bm; float* C; const float* abp; const float* csp;
    int M, N, K, lda, kz, Kc;
    if (z < KS0) { A = A0; Bm = B0; C = C0; abp = ab0p; csp = cs0p; M = M0; N = N0; K = K0; lda = lda0; kz = z; Kc = Kc0; }
    else { A = A1; Bm = B1; C = C1; abp = ab1p; csp = cs1p; M = M1; N = N1; K = K1; lda = lda1; kz = z - KS0; Kc = Kc1; }
    int r0 = blockIdx.x * 64, c0 = blockIdx.y * 64;
    if (r0 >= M || c0 >= N) return;
    int kb = kz * Kc, ke = min(K, kb + Kc);
    __shared__ float As[16][68];
    __shared__ float Bs[16][68];
    int t = threadIdx.x;
    int tx = t & 15, ty = t >> 4;
    float acc[4][4] = {};
    int ar = t >> 2, aq = (t & 3) * 4;
    long abase = (long)(r0 + ar) * lda;
    int brow = t >> 4, bc = (t & 15) * 4;
    // prefetch first K-step
    float4 av = *(const float4*)(A + abase + kb + aq);
    if (abp) {
        float4 abv = *(const float4*)(abp + kb + aq);
        av.x += abv.x; av.y += abv.y; av.z += abv.z; av.w += abv.w;
    }
    float4 bv = *(const float4*)(Bm + (long)(kb + brow) * N + c0 + bc);
    for (int k0 = kb; k0 < ke; k0 += 16) {
        As[aq + 0][ar] = av.x; As[aq + 1][ar] = av.y; As[aq + 2][ar] = av.z; As[aq + 3][ar] = av.w;
        *(float4*)&Bs[brow][bc] = bv;
        __syncthreads();
        if (k0 + 16 < ke) {
            av = *(const float4*)(A + abase + k0 + 16 + aq);
            if (abp) {
                float4 abv = *(const float4*)(abp + k0 + 16 + aq);
                av.x += abv.x; av.y += abv.y; av.z += abv.z; av.w += abv.w;
            }
            bv = *(const float4*)(Bm + (long)(k0 + 16 + brow) * N + c0 + bc);
        }
#pragma unroll
        for (int kk = 0; kk < 16; kk++) {
            float4 a4 = *(const float4*)&As[kk][ty * 4];
            float4 b4 = *(const float4*)&Bs[kk][tx * 4];
            float aa[4] = {a4.x, a4.y, a4.z, a4.w};
            float bb2[4] = {b4.x, b4.y, b4.z, b4.w};
#pragma unroll
            for (int i = 0; i < 4; i++)
#pragma unroll
                for (int j = 0; j < 4; j++) acc[i][j] += aa[i] * bb2[j];
        }
        __syncthreads();
    }
#pragma unroll
    for (int i = 0; i < 4; i++) {
        int row = r0 + ty * 4 + i;
        float sc = csp ? csp[row] : 1.0f;
#pragma unroll
        for (int j = 0; j < 4; j++)
            atomicAdd(&C[(long)row * N + c0 + tx * 4 + j], acc[i][j] * sc);
    }
}

// ---------------- dense-path fused pieces ----------------
__global__ void k_dense_deg2(const float* __restrict__ adj0, float* __restrict__ d0, int n0,
                             const float* __restrict__ adj1, float* __restrict__ d1, int n1) {
    int lane = threadIdx.x & 63;
    int row = (blockIdx.x * blockDim.x + threadIdx.x) >> 6;
    const float* adj; float* dv; int n, r;
    if (row < n0) { adj = adj0; dv = d0; n = n0; r = row; }
    else {
        r = row - n0;
        if (r >= n1) return;
        adj = adj1; dv = d1; n = n1;
    }
    const float* rp = adj + (long)r * n;
    float s = 0.f;
    for (int j = lane; j < n; j += 64) s += rp[j];
    for (int off = 32; off > 0; off >>= 1) s += __shfl_down(s, off, 64);
    if (lane == 0) {
        float deg = s - rp[r] + 1.0f;
        dv[r] = (deg > 0.f) ? 1.0f / sqrtf(deg) : 0.f;
    }
}

__global__ void k_fix_w4(const float* g0, const float* u0, const float* adj0, const float* d0, float* o0, int n0,
                         const float* g1, const float* u1, const float* adj1, const float* d1, float* o1, int n1,
                         const float* __restrict__ b3, const float* __restrict__ W4) {
    __shared__ float dfs[16][68];
    __shared__ float W4s[64 * 16];
    int t = threadIdx.x;
    for (int i = t; i < 1024; i += 256) W4s[i] = W4[i];
    int bx = blockIdx.x, nb0 = n0 / 16;
    const float* g; const float* u; const float* adj; const float* dv; float* o; int n, r0;
    if (bx < nb0) { g = g0; u = u0; adj = adj0; dv = d0; o = o0; n = n0; r0 = bx * 16; }
    else { g = g1; u = u1; adj = adj1; dv = d1; o = o1; n = n1; r0 = (bx - nb0) * 16; }
    int r = t >> 4;
    int row = r0 + r;
    float di = dv[row];
    float om = 1.0f - adj[(long)row * n + row];
    int c4 = (t & 15) * 4;
    float4 gv = *(const float4*)(g + (long)row * 64 + c4);
    float4 uv = *(const float4*)(u + (long)row * 64 + c4);
    float4 bv = *(const float4*)(b3 + c4);
    dfs[r][c4 + 0] = fmaxf(di * (gv.x + om * uv.x) + bv.x, 0.f);
    dfs[r][c4 + 1] = fmaxf(di * (gv.y + om * uv.y) + bv.y, 0.f);
    dfs[r][c4 + 2] = fmaxf(di * (gv.z + om * uv.z) + bv.z, 0.f);
    dfs[r][c4 + 3] = fmaxf(di * (gv.w + om * uv.w) + bv.w, 0.f);
    __syncthreads();
    int c = t & 15;
    float accv = 0.f;
#pragma unroll
    for (int k = 0; k < 64; k++) accv += dfs[r][k] * W4s[k * 16 + c];
    o[row * 16 + c] = di * accv;
}

__global__ void k_fixup2(const float* g0, const float* t0, const float* adj0, const float* d0, float* C0, long n0,
                         const float* g1, const float* t1, const float* adj1, const float* d1, float* C1, long n1,
                         const float* bias, int cols) {
    long idx = (long)blockIdx.x * 256 + threadIdx.x;
    long s0 = n0 * cols;
    const float* g; const float* tt; const float* adj; const float* dv; float* C; long n, li;
    if (idx < s0) { g = g0; tt = t0; adj = adj0; dv = d0; C = C0; n = n0; li = idx; }
    else {
        li = idx - s0;
        if (li >= n1 * cols) return;
        g = g1; tt = t1; adj = adj1; dv = d1; C = C1; n = n1;
    }
    long i = li / cols; int j = li % cols;
    float v = dv[i] * (g[li] + (1.0f - adj[i * n + i]) * tt[li]) + bias[j];
    C[li] = fmaxf(v, 0.f);
}

__global__ void k_adj16(const float* adj0, const float* u0, float* C0, int n0, int KS0, int Kc0,
                        const float* adj1, const float* u1, float* C1, int n1, int KS1, int Kc1) {
    int z = blockIdx.z;
    const float* adj; const float* u; float* C; int n, kz, Kc;
    if (z < KS0) { adj = adj0; u = u0; C = C0; n = n0; kz = z; Kc = Kc0; }
    else { adj = adj1; u = u1; C = C1; n = n1; kz = z - KS0; Kc = Kc1; }
    int r0 = blockIdx.x * 16;
    if (r0 >= n) return;
    int t = threadIdx.x;
    int r = r0 + (t >> 4), c = t & 15;
    int kb = kz * Kc, ke = min(n, kb + Kc);
    const float* arp = adj + (long)r * n;
    float acc = 0.f;
    for (int k = kb; k < ke; k += 4) {
        float4 a = *(const float4*)(arp + k);
        acc += a.x * u[(k + 0) * 16 + c] + a.y * u[(k + 1) * 16 + c]
             + a.z * u[(k + 2) * 16 + c] + a.w * u[(k + 3) * 16 + c];
    }
    atomicAdd(&C[r * 16 + c], acc);
}

// ---------------- stable top-K selection ----------------
__global__ void k_select(const float* __restrict__ cs, int* __restrict__ sel) {
    __shared__ float kk[240];
    int t = threadIdx.x;
    int b0 = blockIdx.x * 4;
    if (t < 240) kk[t] = cs[((long)(b0 * 60 + t)) * 64 + 63];
    __syncthreads();
    if (t < 240) {
        int lb = t / 60, i = t % 60;
        float key = kk[lb * 60 + i];
        int r = 0;
        for (int j = 0; j < 60; j++) {
            float kj = kk[lb * 60 + j];
            r += (kj > key) || (kj == key && j < i);
        }
        if (r < KSEL) sel[(b0 + lb) * KSEL + r] = (b0 + lb) * 60 + i;
    }
}

// ---------------- weight prep (bf16, transposed [out][k]) ----------------
__global__ void k_w2colT(const float* __restrict__ c2w, ushort_t* __restrict__ o) {
    int idx = blockIdx.x * blockDim.x + threadIdx.x;
    if (idx >= 256 * 640) return;
    int oc = idx / 640, q = idx % 640;
    int tap = q >> 7, ic = q & 127;
    o[idx] = f2bf(c2w[(oc * 128 + ic) * 5 + tap]);
}

__global__ void k_w1pT(const float* __restrict__ w, ushort_t* __restrict__ o) {
    int idx = blockIdx.x * blockDim.x + threadIdx.x;
    if (idx >= 128 * 2816) return;
    int j = idx / 2816, c = idx % 2816;
    int tt = c >> 8, oc = c & 255;
    o[idx] = f2bf(w[(oc * 11 + tt) * 128 + j]);
}

// ---------------- lin2 + bn (lin1 bias + relu folded into load) ----------------
__global__ void k_lin2_bn(const float* __restrict__ x, const float* __restrict__ l1b,
                          const float* __restrict__ w,
                          const float* __restrict__ b, const float* __restrict__ g,
                          const float* __restrict__ bb, float* __restrict__ o) {
    int t = blockIdx.x * blockDim.x + threadIdx.x;
    int j = t & 31, bi = t >> 5;
    const float* xr = x + (long)bi * 128;
    float acc = b[j];
    for (int k = 0; k < 128; k++) acc += fmaxf(xr[k] + l1b[k], 0.f) * w[k * 32 + j];
    o[bi * 32 + j] = fmaxf(acc * g[j] + bb[j], 0.f);
}

// ---------------- final fused MLP ----------------
__global__ __launch_bounds__(256) void k_final(const float* __restrict__ hfin, const int* __restrict__ node,
                                               const float* __restrict__ dio, const float* __restrict__ dro,
                                               const float* __restrict__ pp,
                                               const float* __restrict__ fw, const float* __restrict__ fb,
                                               const float* __restrict__ f2w, const float* __restrict__ f2b,
                                               float* __restrict__ out) {
    __shared__ float w[64 * 32];
    __shared__ float w2[32];
    int t = threadIdx.x;
    for (int f = t; f < 2048; f += 256) w[f] = fw[f];
    if (t < 32) w2[t] = f2w[t];
    __syncthreads();
    int b = blockIdx.x * 256 + t;
    float p = *pp, q = 1.0f - p;
    float zin[64];
#pragma unroll
    for (int i = 0; i < 32; i++) zin[i] = hfin[b * 32 + i] * p;
    int n0 = node[b * 2], n1 = node[b * 2 + 1];
#pragma unroll
    for (int i = 0; i < 16; i++) zin[32 + i] = dio[n0 * 16 + i] * q;
#pragma unroll
    for (int i = 0; i < 16; i++) zin[48 + i] = dro[n1 * 16 + i] * q;
    float res = f2b[0];
    for (int j = 0; j < 32; j++) {
        float acc = fb[j];
#pragma unroll
        for (int i = 0; i < 64; i++) acc += zin[i] * w[i * 32 + j];
        res += fmaxf(acc, 0.f) * w2[j];
    }
    out[b] = res;
}

// ---------------- host ----------------
extern "C" void kernel_launch(void* const* d_in, const int* in_sizes, int n_in,
                              void* d_out, int out_size, void* d_ws, size_t ws_size,
                              hipStream_t stream) {
    const float* x        = (const float*)d_in[0];
    const int*   ei       = (const int*)d_in[1];
    const int*   node     = (const int*)d_in[3];
    const float* di_sim   = (const float*)d_in[4];
    const float* dr_sim   = (const float*)d_in[5];
    const float* drug_adj = (const float*)d_in[6];
    const float* dis_adj  = (const float*)d_in[7];
    const float* p        = (const float*)d_in[8];
    const float* W1 = (const float*)d_in[9],  *b1 = (const float*)d_in[10];
    const float* W2 = (const float*)d_in[11], *b2 = (const float*)d_in[12];
    const float* W3 = (const float*)d_in[13], *b3 = (const float*)d_in[14];
    const float* W4 = (const float*)d_in[15], *b4 = (const float*)d_in[16];
    const float* lin_di_w = (const float*)d_in[17], *lin_di_b = (const float*)d_in[18];
    const float* lin_dr_w = (const float*)d_in[19], *lin_dr_b = (const float*)d_in[20];
    const float* c1w = (const float*)d_in[21], *c1b = (const float*)d_in[22];
    const float* c2w = (const float*)d_in[23], *c2b = (const float*)d_in[24];
    const float* lin1w = (const float*)d_in[25], *lin1b = (const float*)d_in[26];
    const float* lin2w = (const float*)d_in[27], *lin2b = (const float*)d_in[28];
    const float* bng = (const float*)d_in[29], *bnb = (const float*)d_in[30];
    const float* fcsw = (const float*)d_in[31], *fcsb = (const float*)d_in[32];
    const float* fcs2w = (const float*)d_in[33], *fcs2b = (const float*)d_in[34];

    char* ws = (char*)d_ws;
    size_t o = 0;
    auto alloc = [&](size_t bytes) { size_t r = o; o += (bytes + 255) & ~(size_t)255; return r; };
    int*   csr     = (int*)(ws + alloc((size_t)NBKT * SEGCAP * 4));   // bucket-strided
    int*   rowp    = (int*)(ws + alloc((size_t)NN * 4));
    int*   degcnt  = (int*)(ws + alloc((size_t)NN * 4));
    float* dinvn   = (float*)(ws + alloc((size_t)NN * 4));
    float* hbuf    = (float*)(ws + alloc((size_t)NN * 32 * 4));  // reused: pool16 + bf16 staging
    float* cs      = (float*)(ws + alloc((size_t)NN * 64 * 4));  // first ~10MB reused as pairs; later act2
    int*   sel     = (int*)(ws + alloc((size_t)NB * KSEL * 4));
    float* hfin    = (float*)(ws + alloc((size_t)NB * 32 * 4));
    ushort_t* w2colT = (ushort_t*)(ws + alloc((size_t)256 * 640 * 2));
    ushort_t* w1pT   = (ushort_t*)(ws + alloc((size_t)128 * 2816 * 2));
    float* ddin_di = (float*)(ws + alloc((size_t)NDRUG * 4));
    float* ddin_dr = (float*)(ws + alloc((size_t)NDIS * 4));
    float* dt2_di  = (float*)(ws + alloc((size_t)NDRUG * 16 * 4));
    float* dt2_dr  = (float*)(ws + alloc((size_t)NDIS * 16 * 4));
    float* do_di   = (float*)(ws + alloc((size_t)NDRUG * 16 * 4));
    float* do_dr   = (float*)(ws + alloc((size_t)NDIS * 16 * 4));
    size_t zbase = o;
    int*   bfill   = (int*)(ws + alloc((size_t)NBKT * 4));
    float* lin1o   = (float*)(ws + alloc((size_t)NB * 128 * 4));
    float* de_di   = (float*)(ws + alloc((size_t)NDRUG * 256 * 4));   // atomic split-K target
    float* de_dr   = (float*)(ws + alloc((size_t)NDIS * 256 * 4));
    float* dt_di   = (float*)(ws + alloc((size_t)NDRUG * 64 * 4));
    float* dt_dr   = (float*)(ws + alloc((size_t)NDIS * 64 * 4));
    float* dg_di   = (float*)(ws + alloc((size_t)NDRUG * 64 * 4));
    float* dg_dr   = (float*)(ws + alloc((size_t)NDIS * 64 * 4));
    float* dg2_di  = (float*)(ws + alloc((size_t)NDRUG * 16 * 4));
    float* dg2_dr  = (float*)(ws + alloc((size_t)NDIS * 16 * 4));
    size_t zsize = o - zbase;
    uint_t* pairsg   = (uint_t*)cs;       // 9.6MB scratch, dead before cs is written
    ushort_t* pool16 = (ushort_t*)hbuf;   // first 15.7MB of hbuf after GCN done
    ushort_t* act2   = (ushort_t*)cs;     // alias after conv1 done
    // bf16 staging in the free tail of hbuf
    char* hb = (char*)hbuf;
    ushort_t* di_sim16 = (ushort_t*)(hb + 15728640);   // 2MB; reused as drugadj16 after de_mfma
    ushort_t* dr_sim16 = (ushort_t*)(hb + 17825792);   // 8MB; reused as disadj16 after de_mfma
    ushort_t* lindiT16 = (ushort_t*)(hb + 26214400);
    ushort_t* lindrT16 = (ushort_t*)(hb + 26738688);
    ushort_t* c1w16    = (ushort_t*)(hb + 27787264);   // 16KB
    ushort_t* uT16_di  = (ushort_t*)(hb + 27811840);   // 128KB
    ushort_t* uT16_dr  = (ushort_t*)(hb + 27942912);   // 256KB
    ushort_t* drugadj16 = di_sim16;
    ushort_t* disadj16  = dr_sim16;

    hipMemsetAsync(ws + zbase, 0, zsize, stream);

    // CSR build: fixed-stride bucket sort (no count/scan passes)
    k_bscatter<<<(NE + CHUNK - 1) / CHUNK, 256, 0, stream>>>(ei, bfill, pairsg);
    k_bbuild<<<NBKT, 256, 0, stream>>>(pairsg, bfill, csr, rowp, degcnt, dinvn);

    // GCN (fp32 — preserves stable sort keys)
    k_xw<<<NN / 64, 256, 0, stream>>>(x, W1, hbuf, 64, 64);
    k_gcn_agg<<<NN / 32, 256, 0, stream>>>(hbuf, csr, rowp, degcnt, dinvn, b1, cs, 0);
    k_xw<<<NN / 64, 256, 0, stream>>>(cs, W2, hbuf, 32, 64);
    k_gcn_agg<<<NN / 32, 256, 0, stream>>>(hbuf, csr, rowp, degcnt, dinvn, b2, cs, 32);

    k_select<<<NB / 4, 256, 0, stream>>>(cs, sel);

    // dense-path front: convert (L2-warm) then de MFMA (split-K for occupancy)
    k_cvt2<<<5120, 256, 0, stream>>>(di_sim, di_sim16, (long)NDRUG * NDRUG,
                                     dr_sim, dr_sim16, (long)NDIS * NDIS);
    k_linwT2<<<dim3(48, 4), 256, 0, stream>>>(lin_di_w, lindiT16, NDRUG,
                                              lin_dr_w, lindrT16, NDIS);
    k_de_mfma<<<dim3(16, 4, 12), 256, 0, stream>>>(
        di_sim16, lindiT16, de_di, lin_di_b, NDRUG, NDRUG, 4,
        dr_sim16, lindrT16, de_dr, lin_dr_b, NDIS, NDIS, 8);
    k_dense_deg2<<<(NDRUG + NDIS) * 64 / 256, 256, 0, stream>>>(drug_adj, ddin_di, NDRUG, dis_adj, ddin_dr, NDIS);
    // adj -> bf16 (reuses sim16 slots; stream-ordered after de_mfma)
    k_cvt2<<<5120, 256, 0, stream>>>(drug_adj, drugadj16, (long)NDRUG * NDRUG,
                                     dis_adj, disadj16, (long)NDIS * NDIS);

    // weight prep
    k_cvt2<<<8, 256, 0, stream>>>(c1w, c1w16, 8192, c1w, c1w16, 0);
    k_w2colT<<<(256 * 640 + 255) / 256, 256, 0, stream>>>(c2w, w2colT);
    k_w1pT<<<(128 * 2816 + 255) / 256, 256, 0, stream>>>(lin1w, w1pT);

    // conv1 via MFMA (gather + relu + pool fused, coalesced flush) -> pool16
    k_conv1_mfma<<<960, 256, 0, stream>>>(cs, sel, c1w16, c1b, pool16);

    // conv2: bf16 MFMA -> act2 bf16 (aliases cs), coalesced C flush
    k_conv2_mfma<<<dim3(352, 2), 256, 0, stream>>>(pool16, w2colT, act2, c2b);

    // lin1: bf16 MFMA split-K -> lin1o fp32 (zeroed)
    k_lin1_mfma<<<dim3(32, 1, 4), 256, 0, stream>>>(act2, w1pT, lin1o);
    k_lin2_bn<<<NB * 32 / 256, 256, 0, stream>>>(lin1o, lin1b, lin2w, lin2b, bng, bnb, hfin);

    // ---- dense drug (p0) + disease (p1) back half ----
    // u = dinv * (de @ W3)   [bias already in de]
    k_gemm_sk<<<dim3(NDIS / 64, 1, 8), 256, 0, stream>>>(
        de_di, W3, dt_di, nullptr, ddin_di, NDRUG, 64, 256, 256, 4, 64,
        de_dr, W3, dt_dr, nullptr, ddin_dr, NDIS, 64, 256, 256, 4, 64);
    // uT bf16 for g-stage
    k_uT2<<<48, 256, 0, stream>>>(dt_di, uT16_di, NDRUG, dt_dr, uT16_dr, NDIS);
    // g = adj @ u via bf16 MFMA (zero-inited dg)
    k_g_mfma<<<dim3(16, 1, 24), 256, 0, stream>>>(
        drugadj16, uT16_di, dg_di, NDRUG, NDRUG, 8,
        disadj16, uT16_dr, dg_dr, NDIS, NDIS, 16);
    k_fix_w4<<<(NDRUG + NDIS) / 16, 256, 0, stream>>>(
        dg_di, dt_di, drug_adj, ddin_di, dt2_di, NDRUG,
        dg_dr, dt_dr, dis_adj, ddin_dr, dt2_dr, NDIS, b3, W4);
    k_adj16<<<dim3(NDIS / 16, 1, 6), 256, 0, stream>>>(
        drug_adj, dt2_di, dg2_di, NDRUG, 2, 512,
        dis_adj, dt2_dr, dg2_dr, NDIS, 4, 512);
    k_fixup2<<<((NDRUG + NDIS) * 16 + 255) / 256, 256, 0, stream>>>(
        dg2_di, dt2_di, drug_adj, ddin_di, do_di, NDRUG,
        dg2_dr, dt2_dr, dis_adj, ddin_dr, do_dr, NDIS, b4, 16);

    k_final<<<NB / 256, 256, 0, stream>>>(hfin, node, do_di, do_dr, p, fcsw, fcsb, fcs2w, fcs2b, (float*)d_out);
}

// Round 26
// 434.028 us; speedup vs baseline: 1.1932x; 1.0250x over previous
//
#include <hip/hip_runtime.h>

#define NN 245760
#define NB 4096
#define NPER 60
#define NE 2000000
#define KSEL 30
#define NDRUG 1024
#define NDIS 2048
#define NBKT 480          // buckets of 512 nodes (NN = 480*512)
#define CHUNK 8192
#define SEGCAP 4992       // max edges per bucket (mean 4167, +12 sigma)

typedef unsigned short ushort_t;
typedef unsigned int uint_t;
using bf16x8 = __attribute__((ext_vector_type(8))) short;
using f32x4 = __attribute__((ext_vector_type(4))) float;

__device__ inline ushort_t f2bf(float f) {
    union { float f; unsigned int u; } v; v.f = f;
    unsigned int r = v.u + 0x7FFF + ((v.u >> 16) & 1);
    return (ushort_t)(r >> 16);
}

// ---------------- CSR build: fixed-stride buckets, 4-batched edge loads ----------------
__global__ __launch_bounds__(256) void k_bscatter(const int* __restrict__ ei,
                                                  int* __restrict__ bfill,
                                                  uint_t* __restrict__ pairs) {
    __shared__ int hist[NBKT], fill[NBKT], gbase[NBKT];
    int t = threadIdx.x;
    long e0 = (long)blockIdx.x * CHUNK;
    int cnt = (int)min((long)CHUNK, (long)NE - e0);
    for (int i = t; i < NBKT; i += 256) { hist[i] = 0; fill[i] = 0; }
    __syncthreads();
    // pass 1: histogram (4 loads in flight per thread)
    for (int i = t; i < cnt; i += 1024) {
        int d[4]; int hv[4];
#pragma unroll
        for (int j = 0; j < 4; j++) {
            int ii = i + j * 256;
            hv[j] = ii < cnt;
            d[j] = hv[j] ? ei[NE + e0 + ii] : 0;
        }
#pragma unroll
        for (int j = 0; j < 4; j++)
            if (hv[j]) atomicAdd(&hist[d[j] >> 9], 1);
    }
    __syncthreads();
    for (int i = t; i < NBKT; i += 256)
        if (hist[i]) gbase[i] = i * SEGCAP + atomicAdd(&bfill[i], hist[i]);
    __syncthreads();
    // pass 2: scatter (4 edge pairs in flight per thread)
    for (int i = t; i < cnt; i += 1024) {
        int s[4], d[4]; int hv[4];
#pragma unroll
        for (int j = 0; j < 4; j++) {
            int ii = i + j * 256;
            hv[j] = ii < cnt;
            if (hv[j]) { s[j] = ei[e0 + ii]; d[j] = ei[NE + e0 + ii]; }
        }
#pragma unroll
        for (int j = 0; j < 4; j++) {
            if (hv[j]) {
                int b = d[j] >> 9;
                int pos = gbase[b] + atomicAdd(&fill[b], 1);
                if (pos < (b + 1) * SEGCAP)
                    pairs[pos] = ((uint_t)s[j] << 9) | (uint_t)(d[j] & 511);
            }
        }
    }
}

__global__ __launch_bounds__(256) void k_bbuild(const uint_t* __restrict__ pairs,
                                                const int* __restrict__ bfill,
                                                int* __restrict__ csr,
                                                int* __restrict__ rowp,
                                                int* __restrict__ cntg,
                                                float* __restrict__ dinv) {
    __shared__ int hist[512], nbase[512], nfill[512], scanA[512], scanB[512];
    __shared__ int seg[SEGCAP];
    int t = threadIdx.x, b = blockIdx.x;
    int ebase = b * SEGCAP;
    int ecnt = bfill[b];
    if (ecnt > SEGCAP) ecnt = SEGCAP;
    for (int i = t; i < 512; i += 256) { hist[i] = 0; nfill[i] = 0; }
    __syncthreads();
    for (int i = t; i < ecnt; i += 256)
        atomicAdd(&hist[pairs[ebase + i] & 511], 1);
    __syncthreads();
    for (int i = t; i < 512; i += 256) scanA[i] = hist[i];
    __syncthreads();
    int* src = scanA; int* dst = scanB;
    for (int off = 1; off < 512; off <<= 1) {
        for (int i = t; i < 512; i += 256)
            dst[i] = src[i] + ((i >= off) ? src[i - off] : 0);
        __syncthreads();
        int* tmp = src; src = dst; dst = tmp;
    }
    for (int i = t; i < 512; i += 256) {
        int h = hist[i];
        int excl = src[i] - h;
        nbase[i] = excl;
        int n = (b << 9) + i;
        rowp[n] = ebase + excl;
        cntg[n] = h;
        dinv[n] = 1.0f / sqrtf((float)h + 1.0f);
    }
    __syncthreads();
    for (int i = t; i < ecnt; i += 256) {
        uint_t v = pairs[ebase + i];
        int ln = v & 511;
        int pos = nbase[ln] + atomicAdd(&nfill[ln], 1);
        if (pos < SEGCAP) seg[pos] = (int)(v >> 9);
    }
    __syncthreads();
    for (int i = t; i < ecnt; i += 256) csr[ebase + i] = seg[i];
}

// ---------------- X(M x K, stride lda) @ W(K x 32) -> h' = dinv * (X@W), K<=64 ----------------
__global__ __launch_bounds__(256) void k_xw(const float* __restrict__ A, const float* __restrict__ W,
                                            const float* __restrict__ dinv,
                                            float* __restrict__ h, int K, int lda) {
    __shared__ float Xs[64][65];
    __shared__ float Ws[64][32];
    int t = threadIdx.x;
    int r0 = blockIdx.x * 64;
    int kq = K >> 2;
    for (int idx = t; idx < 64 * kq; idx += 256) {
        int row = idx / kq, q = idx % kq;
        float4 v = *(const float4*)(A + (long)(r0 + row) * lda + q * 4);
        Xs[row][q * 4 + 0] = v.x; Xs[row][q * 4 + 1] = v.y;
        Xs[row][q * 4 + 2] = v.z; Xs[row][q * 4 + 3] = v.w;
    }
    for (int idx = t; idx < K * 32; idx += 256) ((float*)Ws)[idx] = W[idx];
    __syncthreads();
    int r = (t >> 3) * 2, c = (t & 7) * 4;
    float4 acc0 = {0, 0, 0, 0}, acc1 = {0, 0, 0, 0};
    for (int k = 0; k < K; k++) {
        float x0 = Xs[r][k], x1 = Xs[r + 1][k];
        float4 w = *(const float4*)&Ws[k][c];
        acc0.x += x0 * w.x; acc0.y += x0 * w.y; acc0.z += x0 * w.z; acc0.w += x0 * w.w;
        acc1.x += x1 * w.x; acc1.y += x1 * w.y; acc1.z += x1 * w.z; acc1.w += x1 * w.w;
    }
    float dd0 = dinv[r0 + r], dd1 = dinv[r0 + r + 1];
    acc0.x *= dd0; acc0.y *= dd0; acc0.z *= dd0; acc0.w *= dd0;
    acc1.x *= dd1; acc1.y *= dd1; acc1.z *= dd1; acc1.w *= dd1;
    *(float4*)(h + (long)(r0 + r) * 32 + c) = acc0;
    *(float4*)(h + (long)(r0 + r + 1) * 32 + c) = acc1;
}

// ---------------- GCN aggregation: h pre-scaled by dinv (no per-src dinv gather) ----------------
__global__ void k_gcn_agg(const float* __restrict__ h, const int* __restrict__ csr,
                          const int* __restrict__ rowp, const int* __restrict__ cnt,
                          const float* __restrict__ dinv, const float* __restrict__ bias,
                          float* __restrict__ out, int colofs) {
    int t = threadIdx.x;
    int l = t & 7, g = t >> 3;
    int wl = t & 63;                 // lane within wave
    int gbase = wl & ~7;             // first lane of this 8-lane group
    int d = blockIdx.x * 32 + g;
    float dd = dinv[d];
    int start = rowp[d], c = cnt[d];
    float4 acc = *(const float4*)(h + (long)d * 32 + l * 4);   // = dd*h_d (pre-scaled)
    int k = 0;
    while (k < c) {
        int nb = c - k; if (nb > 8) nb = 8;
        int sl = (l < nb) ? csr[start + k + l] : 0;
        int sj[8]; float4 hj[8];
#pragma unroll
        for (int j = 0; j < 8; j++)
            sj[j] = __shfl(sl, gbase + j, 64);
#pragma unroll
        for (int j = 0; j < 8; j++)
            if (j < nb) hj[j] = *(const float4*)(h + (long)sj[j] * 32 + l * 4);
#pragma unroll
        for (int j = 0; j < 8; j++) {
            if (j < nb) {
                acc.x += hj[j].x;
                acc.y += hj[j].y;
                acc.z += hj[j].z;
                acc.w += hj[j].w;
            }
        }
        k += nb;
    }
    float4 bv = *(const float4*)(bias + l * 4);
    float* op = out + (long)d * 64 + colofs + l * 4;
    op[0] = fmaxf(dd * acc.x + bv.x, 0.f);
    op[1] = fmaxf(dd * acc.y + bv.y, 0.f);
    op[2] = fmaxf(dd * acc.z + bv.z, 0.f);
    op[3] = fmaxf(dd * acc.w + bv.w, 0.f);
}

// ---------------- conv1 via bf16 MFMA: gather + relu + pool, LDS-staged coalesced flush ----------------
__global__ __launch_bounds__(256, 2) void k_conv1_mfma(const float* __restrict__ cs,
                                                       const int* __restrict__ sel,
                                                       const ushort_t* __restrict__ c1w16,
                                                       const float* __restrict__ c1b,
                                                       ushort_t* __restrict__ po16) {
    __shared__ ushort_t A_lds[128 * 72];
    __shared__ ushort_t B_lds[128 * 72];
    int t = threadIdx.x;
    int r0 = blockIdx.x * 128;
#pragma unroll
    for (int rnd = 0; rnd < 4; rnd++) {
        int idx = t + rnd * 256;
        int row = idx >> 3, seg = idx & 7;
        const float* src = cs + (long)sel[r0 + row] * 64 + seg * 8;
        float4 v0 = *(const float4*)src;
        float4 v1 = *(const float4*)(src + 4);
        ushort_t tmp[8] = {f2bf(v0.x), f2bf(v0.y), f2bf(v0.z), f2bf(v0.w),
                           f2bf(v1.x), f2bf(v1.y), f2bf(v1.z), f2bf(v1.w)};
        *(uint4*)&A_lds[row * 72 + seg * 8] = *(uint4*)tmp;
        *(uint4*)&B_lds[row * 72 + seg * 8] = *(const uint4*)(c1w16 + row * 64 + seg * 8);
    }
    __syncthreads();
    int wv = t >> 6, lane = t & 63;
    int wm = wv >> 1, wn = wv & 1;
    int lrow = lane & 15, lk = (lane >> 4) * 8, lr4 = (lane >> 4) * 4;
    f32x4 acc[4][4] = {};
#pragma unroll
    for (int kk = 0; kk < 2; kk++) {
        bf16x8 a[4], b[4];
#pragma unroll
        for (int f = 0; f < 4; f++) {
            a[f] = *(const bf16x8*)&A_lds[(wm * 64 + f * 16 + lrow) * 72 + kk * 32 + lk];
            b[f] = *(const bf16x8*)&B_lds[(wn * 64 + f * 16 + lrow) * 72 + kk * 32 + lk];
        }
#pragma unroll
        for (int i = 0; i < 4; i++)
#pragma unroll
            for (int j = 0; j < 4; j++)
                acc[i][j] = __builtin_amdgcn_mfma_f32_16x16x32_bf16(a[i], b[j], acc[i][j], 0, 0, 0);
    }
    __syncthreads();                       // MFMA operands consumed; reuse A_lds for pooled tile
    ushort_t* po_lds = A_lds;              // 64 x 128 ushorts = 8192 <= 9216
#pragma unroll
    for (int fn = 0; fn < 4; fn++) {
        int col = wn * 64 + fn * 16 + lrow;
        float bb = c1b[col];
#pragma unroll
        for (int fm = 0; fm < 4; fm++) {
            int lrow2 = wm * 32 + fm * 8 + (lr4 >> 1);   // even
            float v0 = fmaxf(acc[fm][fn][0] + bb, 0.f);
            float v1 = fmaxf(acc[fm][fn][1] + bb, 0.f);
            float v2 = fmaxf(acc[fm][fn][2] + bb, 0.f);
            float v3 = fmaxf(acc[fm][fn][3] + bb, 0.f);
            po_lds[lrow2 * 128 + col]       = f2bf(fmaxf(v0, v1));
            po_lds[(lrow2 + 1) * 128 + col] = f2bf(fmaxf(v2, v3));
        }
    }
    __syncthreads();
    uint4* dst = (uint4*)(po16 + (long)(r0 >> 1) * 128);
    const uint4* srcp = (const uint4*)po_lds;
#pragma unroll
    for (int i = 0; i < 4; i++) dst[t + i * 256] = srcp[t + i * 256];
}

// ---------------- conv2: bf16 MFMA im2col GEMM (direct LDS staging, LDS-staged C flush) ----------------
__global__ __launch_bounds__(256, 2) void k_conv2_mfma(const ushort_t* __restrict__ pool16,
                                                       const ushort_t* __restrict__ w2colT,
                                                       ushort_t* __restrict__ act2,
                                                       const float* __restrict__ bias) {
    __shared__ ushort_t smem[2 * 128 * 72];   // A | B ; reused as 128x128 C-tile
    ushort_t* A_lds = smem;
    ushort_t* B_lds = smem + 128 * 72;
    int t = threadIdx.x;
    int r0 = blockIdx.x * 128, c0 = blockIdx.y * 128;
    long abase[4]; const ushort_t* bptr[4]; int lofs[4];
#pragma unroll
    for (int rnd = 0; rnd < 4; rnd++) {
        int idx = t + rnd * 256;
        int row = idx >> 3, seg = idx & 7;
        int arow = r0 + row;
        int bb = arow / 11, tt2 = arow - bb * 11;
        abase[rnd] = (long)(bb * 15 + tt2) * 128 + seg * 8;
        bptr[rnd] = w2colT + (long)(c0 + row) * 640 + seg * 8;
        lofs[rnd] = row * 72 + seg * 8;
    }
    int wv = t >> 6, lane = t & 63;
    int wm = wv >> 1, wn = wv & 1;
    int lrow = lane & 15, lk = (lane >> 4) * 8, lr4 = (lane >> 4) * 4;
    f32x4 acc[4][4] = {};
    for (int k0 = 0; k0 < 640; k0 += 64) {
#pragma unroll
        for (int rnd = 0; rnd < 4; rnd++) {
            *(uint4*)&A_lds[lofs[rnd]] = *(const uint4*)(pool16 + abase[rnd] + k0);
            *(uint4*)&B_lds[lofs[rnd]] = *(const uint4*)(bptr[rnd] + k0);
        }
        __syncthreads();
#pragma unroll
        for (int kk = 0; kk < 2; kk++) {
            bf16x8 a[4], b[4];
#pragma unroll
            for (int f = 0; f < 4; f++) {
                a[f] = *(const bf16x8*)&A_lds[(wm * 64 + f * 16 + lrow) * 72 + kk * 32 + lk];
                b[f] = *(const bf16x8*)&B_lds[(wn * 64 + f * 16 + lrow) * 72 + kk * 32 + lk];
            }
#pragma unroll
            for (int i = 0; i < 4; i++)
#pragma unroll
                for (int j = 0; j < 4; j++)
                    acc[i][j] = __builtin_amdgcn_mfma_f32_16x16x32_bf16(a[i], b[j], acc[i][j], 0, 0, 0);
        }
        __syncthreads();
    }
    // stage C-tile (128x128 bf16) in LDS, flush coalesced
    ushort_t* c_lds = smem;
#pragma unroll
    for (int fn = 0; fn < 4; fn++) {
        int col = wn * 64 + fn * 16 + lrow;
        float bv = bias[c0 + col];
#pragma unroll
        for (int fm = 0; fm < 4; fm++) {
            int lr = wm * 64 + fm * 16 + lr4;
#pragma unroll
            for (int j = 0; j < 4; j++)
                c_lds[(lr + j) * 128 + col] = f2bf(fmaxf(acc[fm][fn][j] + bv, 0.f));
        }
    }
    __syncthreads();
#pragma unroll
    for (int i = 0; i < 8; i++) {
        int idx = t + i * 256;          // 0..2047
        int row = idx >> 4, q = idx & 15;
        *(uint4*)(act2 + (long)(r0 + row) * 256 + c0 + q * 8) = ((const uint4*)c_lds)[idx];
    }
}

// ---------------- lin1: bf16 MFMA split-K, fp32 atomic epilogue (direct LDS staging) ----------------
__global__ __launch_bounds__(256, 2) void k_lin1_mfma(const ushort_t* __restrict__ A,
                                                      const ushort_t* __restrict__ Bm,
                                                      float* __restrict__ C) {
    __shared__ ushort_t A_lds[128 * 72];
    __shared__ ushort_t B_lds[128 * 72];
    int t = threadIdx.x;
    int r0 = blockIdx.x * 128;
    int kz = blockIdx.z;
    const ushort_t* ap[4]; const ushort_t* bp[4]; int lofs[4];
#pragma unroll
    for (int rnd = 0; rnd < 4; rnd++) {
        int idx = t + rnd * 256;
        int row = idx >> 3, seg = idx & 7;
        ap[rnd] = A + (long)(r0 + row) * 2816 + kz * 704 + seg * 8;
        bp[rnd] = Bm + (long)row * 2816 + kz * 704 + seg * 8;
        lofs[rnd] = row * 72 + seg * 8;
    }
    int wv = t >> 6, lane = t & 63;
    int wm = wv >> 1, wn = wv & 1;
    int lrow = lane & 15, lk = (lane >> 4) * 8, lr4 = (lane >> 4) * 4;
    f32x4 acc[4][4] = {};
    for (int k0 = 0; k0 < 704; k0 += 64) {
#pragma unroll
        for (int rnd = 0; rnd < 4; rnd++) {
            *(uint4*)&A_lds[lofs[rnd]] = *(const uint4*)(ap[rnd] + k0);
            *(uint4*)&B_lds[lofs[rnd]] = *(const uint4*)(bp[rnd] + k0);
        }
        __syncthreads();
#pragma unroll
        for (int kk = 0; kk < 2; kk++) {
            bf16x8 a[4], b[4];
#pragma unroll
            for (int f = 0; f < 4; f++) {
                a[f] = *(const bf16x8*)&A_lds[(wm * 64 + f * 16 + lrow) * 72 + kk * 32 + lk];
                b[f] = *(const bf16x8*)&B_lds[(wn * 64 + f * 16 + lrow) * 72 + kk * 32 + lk];
            }
#pragma unroll
            for (int i = 0; i < 4; i++)
#pragma unroll
                for (int j = 0; j < 4; j++)
                    acc[i][j] = __builtin_amdgcn_mfma_f32_16x16x32_bf16(a[i], b[j], acc[i][j], 0, 0, 0);
        }
        __syncthreads();
    }
#pragma unroll
    for (int fn = 0; fn < 4; fn++) {
        int col = wn * 64 + fn * 16 + lrow;
#pragma unroll
        for (int fm = 0; fm < 4; fm++) {
            int rowb = r0 + wm * 64 + fm * 16 + lr4;
#pragma unroll
            for (int j = 0; j < 4; j++)
                atomicAdd(&C[(long)(rowb + j) * 128 + col], acc[fm][fn][j]);
        }
    }
}

// ---------------- de = sim @ lin_w + b : bf16 MFMA, split-K, atomic fp32 epilogue ----------------
__global__ __launch_bounds__(256, 2) void k_de_mfma(
    const ushort_t* __restrict__ A0, const ushort_t* __restrict__ B0, float* __restrict__ C0,
    const float* __restrict__ bias0, int M0, int K0, int KS0,
    const ushort_t* __restrict__ A1, const ushort_t* __restrict__ B1, float* __restrict__ C1,
    const float* __restrict__ bias1, int M1, int K1, int KS1) {
    __shared__ ushort_t A_lds[128 * 72];
    __shared__ ushort_t B_lds[64 * 72];
    int z = blockIdx.z;
    const ushort_t* A; const ushort_t* Bm; float* C; const float* bias; int M, K, kz, KS;
    if (z < KS0) { A = A0; Bm = B0; C = C0; bias = bias0; M = M0; K = K0; kz = z; KS = KS0; }
    else { A = A1; Bm = B1; C = C1; bias = bias1; M = M1; K = K1; kz = z - KS0; KS = KS1; }
    int r0 = blockIdx.x * 128, c0 = blockIdx.y * 64;
    if (r0 >= M) return;
    int Kc = K / KS;
    int kb = kz * Kc;
    int t = threadIdx.x;
    const ushort_t* ap[4]; int alofs[4];
#pragma unroll
    for (int rnd = 0; rnd < 4; rnd++) {
        int idx = t + rnd * 256;
        int row = idx >> 3, seg = idx & 7;
        ap[rnd] = A + (long)(r0 + row) * K + kb + seg * 8;
        alofs[rnd] = row * 72 + seg * 8;
    }
    const ushort_t* bp[2]; int blofs[2];
#pragma unroll
    for (int rnd = 0; rnd < 2; rnd++) {
        int idx = t + rnd * 256;
        int row = idx >> 3, seg = idx & 7;
        bp[rnd] = Bm + (long)(c0 + row) * K + kb + seg * 8;
        blofs[rnd] = row * 72 + seg * 8;
    }
    int wv = t >> 6, lane = t & 63;
    int lrow = lane & 15, lk = (lane >> 4) * 8, lr4 = (lane >> 4) * 4;
    uint4 areg[4], breg[2];
#pragma unroll
    for (int rnd = 0; rnd < 4; rnd++) areg[rnd] = *(const uint4*)(ap[rnd]);
#pragma unroll
    for (int rnd = 0; rnd < 2; rnd++) breg[rnd] = *(const uint4*)(bp[rnd]);
    f32x4 acc[2][4] = {};
    for (int k0 = 0; k0 < Kc; k0 += 64) {
#pragma unroll
        for (int rnd = 0; rnd < 4; rnd++) *(uint4*)&A_lds[alofs[rnd]] = areg[rnd];
#pragma unroll
        for (int rnd = 0; rnd < 2; rnd++) *(uint4*)&B_lds[blofs[rnd]] = breg[rnd];
        __syncthreads();
        if (k0 + 64 < Kc) {
#pragma unroll
            for (int rnd = 0; rnd < 4; rnd++) areg[rnd] = *(const uint4*)(ap[rnd] + k0 + 64);
#pragma unroll
            for (int rnd = 0; rnd < 2; rnd++) breg[rnd] = *(const uint4*)(bp[rnd] + k0 + 64);
        }
#pragma unroll
        for (int kk = 0; kk < 2; kk++) {
            bf16x8 a[2], b[4];
#pragma unroll
            for (int f = 0; f < 2; f++)
                a[f] = *(const bf16x8*)&A_lds[(wv * 32 + f * 16 + lrow) * 72 + kk * 32 + lk];
#pragma unroll
            for (int f = 0; f < 4; f++)
                b[f] = *(const bf16x8*)&B_lds[(f * 16 + lrow) * 72 + kk * 32 + lk];
#pragma unroll
            for (int i = 0; i < 2; i++)
#pragma unroll
                for (int j = 0; j < 4; j++)
                    acc[i][j] = __builtin_amdgcn_mfma_f32_16x16x32_bf16(a[i], b[j], acc[i][j], 0, 0, 0);
        }
        __syncthreads();
    }
#pragma unroll
    for (int fn = 0; fn < 4; fn++) {
        int col = c0 + fn * 16 + lrow;
        float bv = (kz == 0) ? bias[col] : 0.f;
#pragma unroll
        for (int fm = 0; fm < 2; fm++) {
            int rowb = r0 + wv * 32 + fm * 16 + lr4;
#pragma unroll
            for (int j = 0; j < 4; j++)
                atomicAdd(&C[(long)(rowb + j) * 256 + col], acc[fm][fn][j] + bv);
        }
    }
}

// ---------------- g = adj @ u : bf16 MFMA, N=64, split-K, atomic fp32 epilogue ----------------
__global__ __launch_bounds__(256, 2) void k_g_mfma(
    const ushort_t* __restrict__ A0, const ushort_t* __restrict__ B0, float* __restrict__ C0,
    int M0, int K0, int KS0,
    const ushort_t* __restrict__ A1, const ushort_t* __restrict__ B1, float* __restrict__ C1,
    int M1, int K1, int KS1) {
    __shared__ ushort_t A_lds[128 * 72];
    __shared__ ushort_t B_lds[64 * 72];
    int z = blockIdx.z;
    const ushort_t* A; const ushort_t* Bm; float* C; int M, K, kz, KS;
    if (z < KS0) { A = A0; Bm = B0; C = C0; M = M0; K = K0; kz = z; KS = KS0; }
    else { A = A1; Bm = B1; C = C1; M = M1; K = K1; kz = z - KS0; KS = KS1; }
    int r0 = blockIdx.x * 128;
    if (r0 >= M) return;
    int Kc = K / KS;
    int kb = kz * Kc;
    int t = threadIdx.x;
    const ushort_t* ap[4]; int alofs[4];
#pragma unroll
    for (int rnd = 0; rnd < 4; rnd++) {
        int idx = t + rnd * 256;
        int row = idx >> 3, seg = idx & 7;
        ap[rnd] = A + (long)(r0 + row) * K + kb + seg * 8;
        alofs[rnd] = row * 72 + seg * 8;
    }
    const ushort_t* bp[2]; int blofs[2];
#pragma unroll
    for (int rnd = 0; rnd < 2; rnd++) {
        int idx = t + rnd * 256;
        int row = idx >> 3, seg = idx & 7;
        bp[rnd] = Bm + (long)row * K + kb + seg * 8;
        blofs[rnd] = row * 72 + seg * 8;
    }
    int wv = t >> 6, lane = t & 63;
    int lrow = lane & 15, lk = (lane >> 4) * 8, lr4 = (lane >> 4) * 4;
    uint4 areg[4], breg[2];
#pragma unroll
    for (int rnd = 0; rnd < 4; rnd++) areg[rnd] = *(const uint4*)(ap[rnd]);
#pragma unroll
    for (int rnd = 0; rnd < 2; rnd++) breg[rnd] = *(const uint4*)(bp[rnd]);
    f32x4 acc[2][4] = {};
    for (int k0 = 0; k0 < Kc; k0 += 64) {
#pragma unroll
        for (int rnd = 0; rnd < 4; rnd++) *(uint4*)&A_lds[alofs[rnd]] = areg[rnd];
#pragma unroll
        for (int rnd = 0; rnd < 2; rnd++) *(uint4*)&B_lds[blofs[rnd]] = breg[rnd];
        __syncthreads();
        if (k0 + 64 < Kc) {
#pragma unroll
            for (int rnd = 0; rnd < 4; rnd++) areg[rnd] = *(const uint4*)(ap[rnd] + k0 + 64);
#pragma unroll
            for (int rnd = 0; rnd < 2; rnd++) breg[rnd] = *(const uint4*)(bp[rnd] + k0 + 64);
        }
#pragma unroll
        for (int kk = 0; kk < 2; kk++) {
            bf16x8 a[2], b[4];
#pragma unroll
            for (int f = 0; f < 2; f++)
                a[f] = *(const bf16x8*)&A_lds[(wv * 32 + f * 16 + lrow) * 72 + kk * 32 + lk];
#pragma unroll
            for (int f = 0; f < 4; f++)
                b[f] = *(const bf16x8*)&B_lds[(f * 16 + lrow) * 72 + kk * 32 + lk];
#pragma unroll
            for (int i = 0; i < 2; i++)
#pragma unroll
                for (int j = 0; j < 4; j++)
                    acc[i][j] = __builtin_amdgcn_mfma_f32_16x16x32_bf16(a[i], b[j], acc[i][j], 0, 0, 0);
        }
        __syncthreads();
    }
#pragma unroll
    for (int fn = 0; fn < 4; fn++) {
        int col = fn * 16 + lrow;
#pragma unroll
        for (int fm = 0; fm < 2; fm++) {
            int rowb = r0 + wv * 32 + fm * 16 + lr4;
#pragma unroll
            for (int j = 0; j < 4; j++)
                atomicAdd(&C[(long)(rowb + j) * 64 + col], acc[fm][fn][j]);
        }
    }
}

// ---------------- conversions ----------------
__global__ void k_cvt2(const float* __restrict__ a0, ushort_t* __restrict__ o0, long n0,
                       const float* __restrict__ a1, ushort_t* __restrict__ o1, long n1) {
    long i4 = ((long)blockIdx.x * 256 + threadIdx.x) * 4;
    const float* a; ushort_t* o;
    if (i4 < n0) { a = a0 + i4; o = o0 + i4; }
    else {
        long j = i4 - n0;
        if (j >= n1) return;
        a = a1 + j; o = o1 + j;
    }
    float4 v = *(const float4*)a;
    o[0] = f2bf(v.x); o[1] = f2bf(v.y); o[2] = f2bf(v.z); o[3] = f2bf(v.w);
}

// lin_w (K x 256) -> bf16 transposed [n][k]; LDS tile transpose, dual problem
__global__ void k_linwT2(const float* __restrict__ w0, ushort_t* __restrict__ o0, int K0,
                         const float* __restrict__ w1, ushort_t* __restrict__ o1, int K1) {
    __shared__ float tile[64][65];
    int nb0 = K0 / 64;
    int bx = blockIdx.x;
    const float* w; ushort_t* o; int K, kt;
    if (bx < nb0) { w = w0; o = o0; K = K0; kt = bx; }
    else { w = w1; o = o1; K = K1; kt = bx - nb0; }
    int n0 = blockIdx.y * 64, k0 = kt * 64;
    int t = threadIdx.x;
    int r = t >> 6, c = t & 63;
    for (int rr = r; rr < 64; rr += 4)
        tile[rr][c] = w[(long)(k0 + rr) * 256 + n0 + c];
    __syncthreads();
    for (int rr = r; rr < 64; rr += 4)
        o[(long)(n0 + rr) * K + k0 + c] = f2bf(tile[c][rr]);
}

// u (K x 64) -> uT bf16 [64][K]; dual problem
__global__ void k_uT2(const float* __restrict__ u0, ushort_t* __restrict__ o0, int K0,
                      const float* __restrict__ u1, ushort_t* __restrict__ o1, int K1) {
    __shared__ float tile[64][65];
    int nb0 = K0 / 64;
    int bx = blockIdx.x;
    const float* u; ushort_t* o; int K, kt;
    if (bx < nb0) { u = u0; o = o0; K = K0; kt = bx; }
    else { u = u1; o = o1; K = K1; kt = bx - nb0; }
    int k0 = kt * 64;
    int t = threadIdx.x;
    int r = t >> 6, c = t & 63;
    for (int rr = r; rr < 64; rr += 4)
        tile[rr][c] = u[(long)(k0 + rr) * 64 + c];
    __syncthreads();
    for (int rr = r; rr < 64; rr += 4)
        o[(long)rr * K + k0 + c] = f2bf(tile[c][rr]);
}

// ---------------- dual-problem split-K 64x64 GEMM (fp32, register-prefetched K-loop) ----------------
__global__ __launch_bounds__(256) void k_gemm_sk(
    const float* A0, const float* B0, float* C0, const float* ab0p, const float* cs0p,
    int M0, int N0, int K0, int lda0, int KS0, int Kc0,
    const float* A1, const float* B1, float* C1, const float* ab1p, const float* cs1p,
    int M1, int N1, int K1, int lda1, int KS1, int Kc1) {
    int z = blockIdx.z;
    const float* A; const float* Bm; float* C; const float* abp; const float* csp;
    int M, N, K, lda, kz, Kc;
    if (z < KS0) { A = A0; Bm = B0; C = C0; abp = ab0p; csp = cs0p; M = M0; N = N0; K = K0; lda = lda0; kz = z; Kc = Kc0; }
    else { A = A1; Bm = B1; C = C1; abp = ab1p; csp = cs1p; M = M1; N = N1; K = K1; lda = lda1; kz = z - KS0; Kc = Kc1; }
    int r0 = blockIdx.x * 64, c0 = blockIdx.y * 64;
    if (r0 >= M || c0 >= N) return;
    int kb = kz * Kc, ke = min(K, kb + Kc);
    __shared__ float As[16][68];
    __shared__ float Bs[16][68];
    int t = threadIdx.x;
    int tx = t & 15, ty = t >> 4;
    float acc[4][4] = {};
    int ar = t >> 2, aq = (t & 3) * 4;
    long abase = (long)(r0 + ar) * lda;
    int brow = t >> 4, bc = (t & 15) * 4;
    // prefetch first K-step
    float4 av = *(const float4*)(A + abase + kb + aq);
    if (abp) {
        float4 abv = *(const float4*)(abp + kb + aq);
        av.x += abv.x; av.y += abv.y; av.z += abv.z; av.w += abv.w;
    }
    float4 bv = *(const float4*)(Bm + (long)(kb + brow) * N + c0 + bc);
    for (int k0 = kb; k0 < ke; k0 += 16) {
        As[aq + 0][ar] = av.x; As[aq + 1][ar] = av.y; As[aq + 2][ar] = av.z; As[aq + 3][ar] = av.w;
        *(float4*)&Bs[brow][bc] = bv;
        __syncthreads();
        if (k0 + 16 < ke) {
            av = *(const float4*)(A + abase + k0 + 16 + aq);
            if (abp) {
                float4 abv = *(const float4*)(abp + k0 + 16 + aq);
                av.x += abv.x; av.y += abv.y; av.z += abv.z; av.w += abv.w;
            }
            bv = *(const float4*)(Bm + (long)(k0 + 16 + brow) * N + c0 + bc);
        }
#pragma unroll
        for (int kk = 0; kk < 16; kk++) {
            float4 a4 = *(const float4*)&As[kk][ty * 4];
            float4 b4 = *(const float4*)&Bs[kk][tx * 4];
            float aa[4] = {a4.x, a4.y, a4.z, a4.w};
            float bb2[4] = {b4.x, b4.y, b4.z, b4.w};
#pragma unroll
            for (int i = 0; i < 4; i++)
#pragma unroll
                for (int j = 0; j < 4; j++) acc[i][j] += aa[i] * bb2[j];
        }
        __syncthreads();
    }
#pragma unroll
    for (int i = 0; i < 4; i++) {
        int row = r0 + ty * 4 + i;
        float sc = csp ? csp[row] : 1.0f;
#pragma unroll
        for (int j = 0; j < 4; j++)
            atomicAdd(&C[(long)row * N + c0 + tx * 4 + j], acc[i][j] * sc);
    }
}

// ---------------- dense-path fused pieces ----------------
__global__ void k_dense_deg2(const float* __restrict__ adj0, float* __restrict__ d0, int n0,
                             const float* __restrict__ adj1, float* __restrict__ d1, int n1) {
    int lane = threadIdx.x & 63;
    int row = (blockIdx.x * blockDim.x + threadIdx.x) >> 6;
    const float* adj; float* dv; int n, r;
    if (row < n0) { adj = adj0; dv = d0; n = n0; r = row; }
    else {
        r = row - n0;
        if (r >= n1) return;
        adj = adj1; dv = d1; n = n1;
    }
    const float* rp = adj + (long)r * n;
    float s = 0.f;
    for (int j = lane; j < n; j += 64) s += rp[j];
    for (int off = 32; off > 0; off >>= 1) s += __shfl_down(s, off, 64);
    if (lane == 0) {
        float deg = s - rp[r] + 1.0f;
        dv[r] = (deg > 0.f) ? 1.0f / sqrtf(deg) : 0.f;
    }
}

__global__ void k_fix_w4(const float* g0, const float* u0, const float* adj0, const float* d0, float* o0, int n0,
                         const float* g1, const float* u1, const float* adj1, const float* d1, float* o1, int n1,
                         const float* __restrict__ b3, const float* __restrict__ W4) {
    __shared__ float dfs[16][68];
    __shared__ float W4s[64 * 16];
    int t = threadIdx.x;
    for (int i = t; i < 1024; i += 256) W4s[i] = W4[i];
    int bx = blockIdx.x, nb0 = n0 / 16;
    const float* g; const float* u; const float* adj; const float* dv; float* o; int n, r0;
    if (bx < nb0) { g = g0; u = u0; adj = adj0; dv = d0; o = o0; n = n0; r0 = bx * 16; }
    else { g = g1; u = u1; adj = adj1; dv = d1; o = o1; n = n1; r0 = (bx - nb0) * 16; }
    int r = t >> 4;
    int row = r0 + r;
    float di = dv[row];
    float om = 1.0f - adj[(long)row * n + row];
    int c4 = (t & 15) * 4;
    float4 gv = *(const float4*)(g + (long)row * 64 + c4);
    float4 uv = *(const float4*)(u + (long)row * 64 + c4);
    float4 bv = *(const float4*)(b3 + c4);
    dfs[r][c4 + 0] = fmaxf(di * (gv.x + om * uv.x) + bv.x, 0.f);
    dfs[r][c4 + 1] = fmaxf(di * (gv.y + om * uv.y) + bv.y, 0.f);
    dfs[r][c4 + 2] = fmaxf(di * (gv.z + om * uv.z) + bv.z, 0.f);
    dfs[r][c4 + 3] = fmaxf(di * (gv.w + om * uv.w) + bv.w, 0.f);
    __syncthreads();
    int c = t & 15;
    float accv = 0.f;
#pragma unroll
    for (int k = 0; k < 64; k++) accv += dfs[r][k] * W4s[k * 16 + c];
    o[row * 16 + c] = di * accv;
}

__global__ void k_fixup2(const float* g0, const float* t0, const float* adj0, const float* d0, float* C0, long n0,
                         const float* g1, const float* t1, const float* adj1, const float* d1, float* C1, long n1,
                         const float* bias, int cols) {
    long idx = (long)blockIdx.x * 256 + threadIdx.x;
    long s0 = n0 * cols;
    const float* g; const float* tt; const float* adj; const float* dv; float* C; long n, li;
    if (idx < s0) { g = g0; tt = t0; adj = adj0; dv = d0; C = C0; n = n0; li = idx; }
    else {
        li = idx - s0;
        if (li >= n1 * cols) return;
        g = g1; tt = t1; adj = adj1; dv = d1; C = C1; n = n1;
    }
    long i = li / cols; int j = li % cols;
    float v = dv[i] * (g[li] + (1.0f - adj[i * n + i]) * tt[li]) + bias[j];
    C[li] = fmaxf(v, 0.f);
}

__global__ void k_adj16(const float* adj0, const float* u0, float* C0, int n0, int KS0, int Kc0,
                        const float* adj1, const float* u1, float* C1, int n1, int KS1, int Kc1) {
    int z = blockIdx.z;
    const float* adj; const float* u; float* C; int n, kz, Kc;
    if (z < KS0) { adj = adj0; u = u0; C = C0; n = n0; kz = z; Kc = Kc0; }
    else { adj = adj1; u = u1; C = C1; n = n1; kz = z - KS0; Kc = Kc1; }
    int r0 = blockIdx.x * 16;
    if (r0 >= n) return;
    int t = threadIdx.x;
    int r = r0 + (t >> 4), c = t & 15;
    int kb = kz * Kc, ke = min(n, kb + Kc);
    const float* arp = adj + (long)r * n;
    float acc = 0.f;
    for (int k = kb; k < ke; k += 4) {
        float4 a = *(const float4*)(arp + k);
        acc += a.x * u[(k + 0) * 16 + c] + a.y * u[(k + 1) * 16 + c]
             + a.z * u[(k + 2) * 16 + c] + a.w * u[(k + 3) * 16 + c];
    }
    atomicAdd(&C[r * 16 + c], acc);
}

// ---------------- stable top-K selection ----------------
__global__ void k_select(const float* __restrict__ cs, int* __restrict__ sel) {
    __shared__ float kk[240];
    int t = threadIdx.x;
    int b0 = blockIdx.x * 4;
    if (t < 240) kk[t] = cs[((long)(b0 * 60 + t)) * 64 + 63];
    __syncthreads();
    if (t < 240) {
        int lb = t / 60, i = t % 60;
        float key = kk[lb * 60 + i];
        int r = 0;
        for (int j = 0; j < 60; j++) {
            float kj = kk[lb * 60 + j];
            r += (kj > key) || (kj == key && j < i);
        }
        if (r < KSEL) sel[(b0 + lb) * KSEL + r] = (b0 + lb) * 60 + i;
    }
}

// ---------------- weight prep (bf16, transposed [out][k]) ----------------
__global__ void k_w2colT(const float* __restrict__ c2w, ushort_t* __restrict__ o) {
    int idx = blockIdx.x * blockDim.x + threadIdx.x;
    if (idx >= 256 * 640) return;
    int oc = idx / 640, q = idx % 640;
    int tap = q >> 7, ic = q & 127;
    o[idx] = f2bf(c2w[(oc * 128 + ic) * 5 + tap]);
}

__global__ void k_w1pT(const float* __restrict__ w, ushort_t* __restrict__ o) {
    int idx = blockIdx.x * blockDim.x + threadIdx.x;
    if (idx >= 128 * 2816) return;
    int j = idx / 2816, c = idx % 2816;
    int tt = c >> 8, oc = c & 255;
    o[idx] = f2bf(w[(oc * 11 + tt) * 128 + j]);
}

// ---------------- lin2 + bn (lin1 bias + relu folded into load) ----------------
__global__ void k_lin2_bn(const float* __restrict__ x, const float* __restrict__ l1b,
                          const float* __restrict__ w,
                          const float* __restrict__ b, const float* __restrict__ g,
                          const float* __restrict__ bb, float* __restrict__ o) {
    int t = blockIdx.x * blockDim.x + threadIdx.x;
    int j = t & 31, bi = t >> 5;
    const float* xr = x + (long)bi * 128;
    float acc = b[j];
    for (int k = 0; k < 128; k++) acc += fmaxf(xr[k] + l1b[k], 0.f) * w[k * 32 + j];
    o[bi * 32 + j] = fmaxf(acc * g[j] + bb[j], 0.f);
}

// ---------------- final fused MLP ----------------
__global__ __launch_bounds__(256) void k_final(const float* __restrict__ hfin, const int* __restrict__ node,
                                               const float* __restrict__ dio, const float* __restrict__ dro,
                                               const float* __restrict__ pp,
                                               const float* __restrict__ fw, const float* __restrict__ fb,
                                               const float* __restrict__ f2w, const float* __restrict__ f2b,
                                               float* __restrict__ out) {
    __shared__ float w[64 * 32];
    __shared__ float w2[32];
    int t = threadIdx.x;
    for (int f = t; f < 2048; f += 256) w[f] = fw[f];
    if (t < 32) w2[t] = f2w[t];
    __syncthreads();
    int b = blockIdx.x * 256 + t;
    float p = *pp, q = 1.0f - p;
    float zin[64];
#pragma unroll
    for (int i = 0; i < 32; i++) zin[i] = hfin[b * 32 + i] * p;
    int n0 = node[b * 2], n1 = node[b * 2 + 1];
#pragma unroll
    for (int i = 0; i < 16; i++) zin[32 + i] = dio[n0 * 16 + i] * q;
#pragma unroll
    for (int i = 0; i < 16; i++) zin[48 + i] = dro[n1 * 16 + i] * q;
    float res = f2b[0];
    for (int j = 0; j < 32; j++) {
        float acc = fb[j];
#pragma unroll
        for (int i = 0; i < 64; i++) acc += zin[i] * w[i * 32 + j];
        res += fmaxf(acc, 0.f) * w2[j];
    }
    out[b] = res;
}

// ---------------- host ----------------
extern "C" void kernel_launch(void* const* d_in, const int* in_sizes, int n_in,
                              void* d_out, int out_size, void* d_ws, size_t ws_size,
                              hipStream_t stream) {
    const float* x        = (const float*)d_in[0];
    const int*   ei       = (const int*)d_in[1];
    const int*   node     = (const int*)d_in[3];
    const float* di_sim   = (const float*)d_in[4];
    const float* dr_sim   = (const float*)d_in[5];
    const float* drug_adj = (const float*)d_in[6];
    const float* dis_adj  = (const float*)d_in[7];
    const float* p        = (const float*)d_in[8];
    const float* W1 = (const float*)d_in[9],  *b1 = (const float*)d_in[10];
    const float* W2 = (const float*)d_in[11], *b2 = (const float*)d_in[12];
    const float* W3 = (const float*)d_in[13], *b3 = (const float*)d_in[14];
    const float* W4 = (const float*)d_in[15], *b4 = (const float*)d_in[16];
    const float* lin_di_w = (const float*)d_in[17], *lin_di_b = (const float*)d_in[18];
    const float* lin_dr_w = (const float*)d_in[19], *lin_dr_b = (const float*)d_in[20];
    const float* c1w = (const float*)d_in[21], *c1b = (const float*)d_in[22];
    const float* c2w = (const float*)d_in[23], *c2b = (const float*)d_in[24];
    const float* lin1w = (const float*)d_in[25], *lin1b = (const float*)d_in[26];
    const float* lin2w = (const float*)d_in[27], *lin2b = (const float*)d_in[28];
    const float* bng = (const float*)d_in[29], *bnb = (const float*)d_in[30];
    const float* fcsw = (const float*)d_in[31], *fcsb = (const float*)d_in[32];
    const float* fcs2w = (const float*)d_in[33], *fcs2b = (const float*)d_in[34];

    char* ws = (char*)d_ws;
    size_t o = 0;
    auto alloc = [&](size_t bytes) { size_t r = o; o += (bytes + 255) & ~(size_t)255; return r; };
    int*   csr     = (int*)(ws + alloc((size_t)NBKT * SEGCAP * 4));   // bucket-strided
    int*   rowp    = (int*)(ws + alloc((size_t)NN * 4));
    int*   degcnt  = (int*)(ws + alloc((size_t)NN * 4));
    float* dinvn   = (float*)(ws + alloc((size_t)NN * 4));
    float* hbuf    = (float*)(ws + alloc((size_t)NN * 32 * 4));  // reused: pool16 + bf16 staging
    float* cs      = (float*)(ws + alloc((size_t)NN * 64 * 4));  // first ~10MB reused as pairs; later act2
    int*   sel     = (int*)(ws + alloc((size_t)NB * KSEL * 4));
    float* hfin    = (float*)(ws + alloc((size_t)NB * 32 * 4));
    ushort_t* w2colT = (ushort_t*)(ws + alloc((size_t)256 * 640 * 2));
    ushort_t* w1pT   = (ushort_t*)(ws + alloc((size_t)128 * 2816 * 2));
    float* ddin_di = (float*)(ws + alloc((size_t)NDRUG * 4));
    float* ddin_dr = (float*)(ws + alloc((size_t)NDIS * 4));
    float* dt2_di  = (float*)(ws + alloc((size_t)NDRUG * 16 * 4));
    float* dt2_dr  = (float*)(ws + alloc((size_t)NDIS * 16 * 4));
    float* do_di   = (float*)(ws + alloc((size_t)NDRUG * 16 * 4));
    float* do_dr   = (float*)(ws + alloc((size_t)NDIS * 16 * 4));
    size_t zbase = o;
    int*   bfill   = (int*)(ws + alloc((size_t)NBKT * 4));
    float* lin1o   = (float*)(ws + alloc((size_t)NB * 128 * 4));
    float* de_di   = (float*)(ws + alloc((size_t)NDRUG * 256 * 4));   // atomic split-K target
    float* de_dr   = (float*)(ws + alloc((size_t)NDIS * 256 * 4));
    float* dt_di   = (float*)(ws + alloc((size_t)NDRUG * 64 * 4));
    float* dt_dr   = (float*)(ws + alloc((size_t)NDIS * 64 * 4));
    float* dg_di   = (float*)(ws + alloc((size_t)NDRUG * 64 * 4));
    float* dg_dr   = (float*)(ws + alloc((size_t)NDIS * 64 * 4));
    float* dg2_di  = (float*)(ws + alloc((size_t)NDRUG * 16 * 4));
    float* dg2_dr  = (float*)(ws + alloc((size_t)NDIS * 16 * 4));
    size_t zsize = o - zbase;
    uint_t* pairsg   = (uint_t*)cs;       // 9.6MB scratch, dead before cs is written
    ushort_t* pool16 = (ushort_t*)hbuf;   // first 15.7MB of hbuf after GCN done
    ushort_t* act2   = (ushort_t*)cs;     // alias after conv1 done
    // bf16 staging in the free tail of hbuf
    char* hb = (char*)hbuf;
    ushort_t* di_sim16 = (ushort_t*)(hb + 15728640);   // 2MB; reused as drugadj16 after de_mfma
    ushort_t* dr_sim16 = (ushort_t*)(hb + 17825792);   // 8MB; reused as disadj16 after de_mfma
    ushort_t* lindiT16 = (ushort_t*)(hb + 26214400);
    ushort_t* lindrT16 = (ushort_t*)(hb + 26738688);
    ushort_t* c1w16    = (ushort_t*)(hb + 27787264);   // 16KB
    ushort_t* uT16_di  = (ushort_t*)(hb + 27811840);   // 128KB
    ushort_t* uT16_dr  = (ushort_t*)(hb + 27942912);   // 256KB
    ushort_t* drugadj16 = di_sim16;
    ushort_t* disadj16  = dr_sim16;

    hipMemsetAsync(ws + zbase, 0, zsize, stream);

    // CSR build: fixed-stride bucket sort (no count/scan passes)
    k_bscatter<<<(NE + CHUNK - 1) / CHUNK, 256, 0, stream>>>(ei, bfill, pairsg);
    k_bbuild<<<NBKT, 256, 0, stream>>>(pairsg, bfill, csr, rowp, degcnt, dinvn);

    // GCN (fp32, h pre-scaled by dinv — bit-identical math, no per-src dinv gather)
    k_xw<<<NN / 64, 256, 0, stream>>>(x, W1, dinvn, hbuf, 64, 64);
    k_gcn_agg<<<NN / 32, 256, 0, stream>>>(hbuf, csr, rowp, degcnt, dinvn, b1, cs, 0);
    k_xw<<<NN / 64, 256, 0, stream>>>(cs, W2, dinvn, hbuf, 32, 64);
    k_gcn_agg<<<NN / 32, 256, 0, stream>>>(hbuf, csr, rowp, degcnt, dinvn, b2, cs, 32);

    k_select<<<NB / 4, 256, 0, stream>>>(cs, sel);

    // dense-path front: convert (L2-warm) then de MFMA (split-K for occupancy)
    k_cvt2<<<5120, 256, 0, stream>>>(di_sim, di_sim16, (long)NDRUG * NDRUG,
                                     dr_sim, dr_sim16, (long)NDIS * NDIS);
    k_linwT2<<<dim3(48, 4), 256, 0, stream>>>(lin_di_w, lindiT16, NDRUG,
                                              lin_dr_w, lindrT16, NDIS);
    k_de_mfma<<<dim3(16, 4, 12), 256, 0, stream>>>(
        di_sim16, lindiT16, de_di, lin_di_b, NDRUG, NDRUG, 4,
        dr_sim16, lindrT16, de_dr, lin_dr_b, NDIS, NDIS, 8);
    k_dense_deg2<<<(NDRUG + NDIS) * 64 / 256, 256, 0, stream>>>(drug_adj, ddin_di, NDRUG, dis_adj, ddin_dr, NDIS);
    // adj -> bf16 (reuses sim16 slots; stream-ordered after de_mfma)
    k_cvt2<<<5120, 256, 0, stream>>>(drug_adj, drugadj16, (long)NDRUG * NDRUG,
                                     dis_adj, disadj16, (long)NDIS * NDIS);

    // weight prep
    k_cvt2<<<8, 256, 0, stream>>>(c1w, c1w16, 8192, c1w, c1w16, 0);
    k_w2colT<<<(256 * 640 + 255) / 256, 256, 0, stream>>>(c2w, w2colT);
    k_w1pT<<<(128 * 2816 + 255) / 256, 256, 0, stream>>>(lin1w, w1pT);

    // conv1 via MFMA (gather + relu + pool fused, coalesced flush) -> pool16
    k_conv1_mfma<<<960, 256, 0, stream>>>(cs, sel, c1w16, c1b, pool16);

    // conv2: bf16 MFMA -> act2 bf16 (aliases cs), coalesced C flush
    k_conv2_mfma<<<dim3(352, 2), 256, 0, stream>>>(pool16, w2colT, act2, c2b);

    // lin1: bf16 MFMA split-K -> lin1o fp32 (zeroed)
    k_lin1_mfma<<<dim3(32, 1, 4), 256, 0, stream>>>(act2, w1pT, lin1o);
    k_lin2_bn<<<NB * 32 / 256, 256, 0, stream>>>(lin1o, lin1b, lin2w, lin2b, bng, bnb, hfin);

    // ---- dense drug (p0) + disease (p1) back half ----
    // u = dinv * (de @ W3)   [bias already in de]
    k_gemm_sk<<<dim3(NDIS / 64, 1, 8), 256, 0, stream>>>(
        de_di, W3, dt_di, nullptr, ddin_di, NDRUG, 64, 256, 256, 4, 64,
        de_dr, W3, dt_dr, nullptr, ddin_dr, NDIS, 64, 256, 256, 4, 64);
    // uT bf16 for g-stage
    k_uT2<<<48, 256, 0, stream>>>(dt_di, uT16_di, NDRUG, dt_dr, uT16_dr, NDIS);
    // g = adj @ u via bf16 MFMA (zero-inited dg)
    k_g_mfma<<<dim3(16, 1, 24), 256, 0, stream>>>(
        drugadj16, uT16_di, dg_di, NDRUG, NDRUG, 8,
        disadj16, uT16_dr, dg_dr, NDIS, NDIS, 16);
    k_fix_w4<<<(NDRUG + NDIS) / 16, 256, 0, stream>>>(
        dg_di, dt_di, drug_adj, ddin_di, dt2_di, NDRUG,
        dg_dr, dt_dr, dis_adj, ddin_dr, dt2_dr, NDIS, b3, W4);
    k_adj16<<<dim3(NDIS / 16, 1, 6), 256, 0, stream>>>(
        drug_adj, dt2_di, dg2_di, NDRUG, 2, 512,
        dis_adj, dt2_dr, dg2_dr, NDIS, 4, 512);
    k_fixup2<<<((NDRUG + NDIS) * 16 + 255) / 256, 256, 0, stream>>>(
        dg2_di, dt2_di, drug_adj, ddin_di, do_di, NDRUG,
        dg2_dr, dt2_dr, dis_adj, ddin_dr, do_dr, NDIS, b4, 16);

    k_final<<<NB / 256, 256, 0, stream>>>(hfin, node, do_di, do_dr, p, fcsw, fcsb, fcs2w, fcs2b, (float*)d_out);
}